// Round 14
// baseline (427.253 us; speedup 1.0000x reference)
//
#include <hip/hip_runtime.h>

// MoE layer: B=4,T=1024,C=1024,H=4096,E=8, top-2 routing, shared expert.
// Sparse formulation: only top-2 experts per token are computed.
//
// R14: B-path pipeline depth 1 -> 2 via DOUBLE register buffer (bqA/bqB,
// statically alternated by a 2-step unrolled loop -- no runtime reg indexing).
// LOAD_B(t+2) now issues in the tile BODY (after STAGE_A); the tail's
// WAITVM(18) drains only B(t+1) -- which is ~2 tile bodies old => near-zero
// stall -- keeping [A(t+2),B(t+2)]=18 in flight. R13 showed gemm_h is
// latency-bound (FETCH 291->200MB, dur unchanged); R11 showed draining early
// without a 2nd buffer stalls ahead of independent MFMAs. This is the
// remaining correct fix. Everything else byte-identical to R13 (415us).

typedef unsigned short u16;
typedef __bf16 bf16x8 __attribute__((ext_vector_type(8)));
typedef float f32x4 __attribute__((ext_vector_type(4)));
typedef u16 u16x8 __attribute__((ext_vector_type(8)));

#define NTOK 4096
#define CDIM 1024
#define HDIM 4096
#define NEXP 8
#define SLOTS 14336   // 4096 shared (16 tiles) + 10240 routed capacity (256-aligned segs)
#define NTILES 56     // SLOTS/256
#define RBLK 1024     // router grid (4 tokens/block)

#define WAITVM(N) do { asm volatile("s_waitcnt vmcnt(" #N ")" ::: "memory"); } while (0)
#define WAITLGKM do { asm volatile("s_waitcnt lgkmcnt(0)" ::: "memory"); } while (0)

static __device__ __forceinline__ u16 f2bf(float f) {   // round-to-nearest-even
  unsigned u = __float_as_uint(f);
  u += 0x7fffu + ((u >> 16) & 1u);
  return (u16)(u >> 16);
}

static __device__ __forceinline__ void gload16(const void* g, void* l) {
  __builtin_amdgcn_global_load_lds((const __attribute__((address_space(1))) unsigned int*)g,
                                   (__attribute__((address_space(3))) unsigned int*)l,
                                   16, 0, 0);
}

// ---------------- init: zero cursor, identity/pad slot map ----------------
__global__ void init_kernel(int* order, int* tile_expert, int* cursor) {
  int i = blockIdx.x * 256 + threadIdx.x;      // grid 56*256 = 14336
  if (i < SLOTS) order[i] = (i < NTOK) ? i : -1;
  if (i < NTILES) tile_expert[i] = (i < 16) ? 8 : -1;   // tiles 0..15 = shared expert
  if (i < NEXP) cursor[i] = 0;
}

// ---------------- router + X->bf16 fused: 1 wave/token, NO global atomics ----------------
__global__ __launch_bounds__(256) void router_kernel(
    const float* __restrict__ X, const float* __restrict__ rw,
    u16* __restrict__ Xb,
    float* __restrict__ w01, int* __restrict__ e01,
    float* __restrict__ pP, int* __restrict__ pC) {
  __shared__ float wP[4][8];
  __shared__ int wE[4][2];
  const int tid = threadIdx.x;
  const int w = tid >> 6, l = tid & 63;
  const int wid = blockIdx.x * 4 + w;   // token
  const float* x = X + (size_t)wid * CDIM;
  u16* xbrow = Xb + (size_t)wid * CDIM;
  float s[8] = {0.f,0.f,0.f,0.f,0.f,0.f,0.f,0.f};
#pragma unroll 4
  for (int i = 0; i < 16; ++i) {
    int c = i * 64 + l;
    float xv = x[c];
    xbrow[c] = f2bf(xv);                // fused bf16 conversion
    const float4* rp = (const float4*)(rw + c * 8);
    float4 r0 = rp[0], r1 = rp[1];
    s[0] += xv * r0.x; s[1] += xv * r0.y; s[2] += xv * r0.z; s[3] += xv * r0.w;
    s[4] += xv * r1.x; s[5] += xv * r1.y; s[6] += xv * r1.z; s[7] += xv * r1.w;
  }
#pragma unroll
  for (int off = 32; off; off >>= 1)
#pragma unroll
    for (int e = 0; e < 8; ++e) s[e] += __shfl_down(s[e], off);
  if (l == 0) {
    float m = s[0];
#pragma unroll
    for (int e = 1; e < 8; ++e) m = fmaxf(m, s[e]);
    float p[8], d = 0.f;
#pragma unroll
    for (int e = 0; e < 8; ++e) { p[e] = expf(s[e] - m); d += p[e]; }
    float inv = 1.f / d;
#pragma unroll
    for (int e = 0; e < 8; ++e) p[e] *= inv;
    int e0 = 0;
#pragma unroll
    for (int e = 1; e < 8; ++e) if (p[e] > p[e0]) e0 = e;   // ties -> lowest idx (jax)
    int e1 = -1;
#pragma unroll
    for (int e = 0; e < 8; ++e) if (e != e0 && (e1 < 0 || p[e] > p[e1])) e1 = e;
    w01[wid * 2] = p[e0]; w01[wid * 2 + 1] = p[e1];
    e01[wid * 2] = e0;    e01[wid * 2 + 1] = e1;
#pragma unroll
    for (int e = 0; e < 8; ++e) wP[w][e] = p[e];
    wE[w][0] = e0; wE[w][1] = e1;
  }
  __syncthreads();
  if (tid < 8) {
    pP[blockIdx.x * 8 + tid] = wP[0][tid] + wP[1][tid] + wP[2][tid] + wP[3][tid];
    int c = 0;
#pragma unroll
    for (int v = 0; v < 4; ++v) c += (wE[v][0] == tid) + (wE[v][1] == tid);
    pC[blockIdx.x * 8 + tid] = c;
  }
}

// ---------------- setup: reduce partials, offsets (256-aligned), tile map, aux ----------------
__global__ __launch_bounds__(256) void setup_kernel(
    const float* __restrict__ pP, const int* __restrict__ pC,
    int* __restrict__ roff, int* __restrict__ tile_expert, float* __restrict__ out_aux) {
  __shared__ float sP[32][8];
  __shared__ int   sC[32][8];
  const int tid = threadIdx.x;
  const int e = tid & 7, g = tid >> 3;   // 32 groups x 8 experts
  float fs = 0.f; int cs = 0;
  for (int b = g; b < RBLK; b += 32) { fs += pP[b * 8 + e]; cs += pC[b * 8 + e]; }
  sP[g][e] = fs; sC[g][e] = cs;
  __syncthreads();
  if (tid == 0) {
    float P[8]; int C[8];
    for (int e2 = 0; e2 < 8; ++e2) {
      float f2 = 0.f; int c2 = 0;
      for (int g2 = 0; g2 < 32; ++g2) { f2 += sP[g2][e2]; c2 += sC[g2][e2]; }
      P[e2] = f2; C[e2] = c2;
    }
    int off = NTOK;
    float a = 0.f;
    for (int e2 = 0; e2 < NEXP; ++e2) {
      roff[e2] = off;
      int nt = (C[e2] + 255) >> 8;
      int t0 = off >> 8;
      for (int i = 0; i < nt; ++i) tile_expert[t0 + i] = e2;
      off += nt << 8;
      a += (C[e2] * (1.f / NTOK)) * (P[e2] * (1.f / NTOK));
    }
    out_aux[0] = (float)NEXP * a;
  }
}

// ---------------- scatter: token -> slots, block-aggregated cursor ----------------
__global__ __launch_bounds__(256) void scatter_kernel(
    const int* __restrict__ e01, const int* __restrict__ roff,
    int* __restrict__ cursor, int* __restrict__ order, int* __restrict__ slot_of) {
  __shared__ int cnt_l[8];
  __shared__ int base_l[8];
  const int tid = threadIdx.x;
  const int t = blockIdx.x * 256 + tid;   // grid 16 blocks
  if (tid < 8) cnt_l[tid] = 0;
  __syncthreads();
  int e0 = e01[t * 2], e1 = e01[t * 2 + 1];
  int p0 = atomicAdd(&cnt_l[e0], 1);      // LDS atomics
  int p1 = atomicAdd(&cnt_l[e1], 1);
  __syncthreads();
  if (tid < 8) base_l[tid] = atomicAdd(&cursor[tid], cnt_l[tid]);  // 8 global atomics/block
  __syncthreads();
  int s0 = roff[e0] + base_l[e0] + p0;
  int s1 = roff[e1] + base_l[e1] + p1;
  order[s0] = t; order[s1] = t;
  slot_of[t * 2] = s0; slot_of[t * 2 + 1] = s1;
}

// LDS layout (both GEMMs): per 256x32 operand K-tile, 1KB chunks. Chunk g =
// rows 16g..16g+15; slot l = (row 16g+(l&15), k (l>>4)*8..+7). A staged by
// gload16 (3 bufs, distance 2); B staged via regs (bqA/bqB double-buffer,
// distance 2): lane l loads 16 fp32 (k = kt*32+(l>>5)*16+j, n = n0+32w+(l&31)),
// converts, writes 2 b128. All LDS ops wave-uniform-base + disjoint 16B slots
// -> zero bank conflicts (verified R3-R13).

// ---------------- GEMM1: hidden = relu(A @ W1 + b1), W1 fp32 [C][H], out bf16 ----------------
__global__ __launch_bounds__(512, 2) void gemm_h_kernel(
    const u16* __restrict__ Xb, const float* __restrict__ W1, const float* __restrict__ RW1,
    const float* __restrict__ sh_b1, const float* __restrict__ rt_b1,
    const int* __restrict__ tile_expert, const int* __restrict__ order,
    u16* __restrict__ Hu) {
  // bijective XCD swizzle, TILE-FAST decode (R13): B-panel L2 reuse
  const int orig = blockIdx.y * 16 + blockIdx.x;
  const int wg = (orig & 7) * 112 + (orig >> 3);
  const int tile = wg % 56, nidx = wg / 56;
  int e = tile_expert[tile];
  if (e < 0) return;
  const float* Bw = (e == 8) ? W1 : RW1 + (size_t)e * CDIM * HDIM;   // [C][H] fp32
  const float* bias = (e == 8) ? sh_b1 : rt_b1 + e * HDIM;

  __shared__ u16 LDS[40960];   // 80KB: A 3x8192 + B 2x8192; epilogue [128][264]
  u16* As = LDS;
  u16* Bs = LDS + 24576;

  const int tid = threadIdx.x;
  const int l = tid & 63, w = tid >> 6;     // 8 waves
  const int wm = w >> 2, wn = w & 3;        // 2M x 4N (wave tile 128x64)
  const int fr = l & 15, fq = l >> 4;
  const int m0 = tile * 256, n0 = nidx * 256;

  int tok0 = order[m0 + 32 * w + fr];      if (tok0 < 0) tok0 = 0;
  int tok1 = order[m0 + 32 * w + 16 + fr]; if (tok1 < 0) tok1 = 0;
  const u16* aSrc0 = Xb + (size_t)tok0 * CDIM + fq * 8;
  const u16* aSrc1 = Xb + (size_t)tok1 * CDIM + fq * 8;
  auto STAGE_A = [&](int bi, int kofs) {
    gload16(aSrc0 + kofs, As + bi * 8192 + (2 * w + 0) * 512);
    gload16(aSrc1 + kofs, As + bi * 8192 + (2 * w + 1) * 512);
  };

  // B: fp32 [CDIM][HDIM]; lane covers n = n0+32w+(l&31), k base (l>>5)*16
  const float* bSrc = Bw + (size_t)((l >> 5) * 16) * HDIM + (n0 + 32 * w + (l & 31));
  float bqA[16], bqB[16];
  auto LOAD_B = [&](int kt, float (&bq)[16]) {
    const float* s = bSrc + (size_t)kt * 32 * HDIM;
#pragma unroll
    for (int j = 0; j < 16; ++j) bq[j] = s[(size_t)j * HDIM];
  };
  u16* bBase = Bs + (2 * w + ((l & 31) >> 4)) * 512 + (l & 15) * 8 + (l >> 5) * 256;
  auto WRITE_B = [&](int bi, const float (&bq)[16]) {
    u16x8 v0, v1;
#pragma unroll
    for (int j = 0; j < 8; ++j) { v0[j] = f2bf(bq[j]); v1[j] = f2bf(bq[8 + j]); }
    *(u16x8*)(bBase + bi * 8192) = v0;
    *(u16x8*)(bBase + bi * 8192 + 128) = v1;
  };

  float bvf[4];
#pragma unroll
  for (int j = 0; j < 4; ++j) bvf[j] = bias[n0 + wn * 64 + j * 16 + fr];

  f32x4 acc[8][4] = {};
  const int NT = CDIM / 32;   // 32 (even)

  // tile body: LOAD_B(t+2) issues EARLY (with STAGE_A); tail drains only
  // B(t+1) (2 tiles old) via WAITVM(18) = [A(t+2)=2 + B(t+2)=16] kept.
  auto TILE = [&](int t, float (&bqL)[16], float (&bqW)[16]) {
    if (t + 2 < NT) { STAGE_A((t + 2) % 3, (t + 2) * 32); LOAD_B(t + 2, bqL); }
    const u16* ab = As + (t % 3) * 8192 + l * 8;
    const u16* bb = Bs + (t & 1) * 8192 + l * 8;
    bf16x8 av[4], bv[4], aw[4];
#pragma unroll
    for (int j = 0; j < 4; ++j) bv[j] = *(const bf16x8*)&bb[(wn * 4 + j) * 512];
#pragma unroll
    for (int i = 0; i < 4; ++i) av[i] = *(const bf16x8*)&ab[(wm * 8 + i) * 512];
#pragma unroll
    for (int i = 0; i < 4; ++i) aw[i] = *(const bf16x8*)&ab[(wm * 8 + 4 + i) * 512];
    __builtin_amdgcn_s_setprio(1);
#pragma unroll
    for (int i = 0; i < 4; ++i)
#pragma unroll
      for (int j = 0; j < 4; ++j)
        acc[i][j] = __builtin_amdgcn_mfma_f32_16x16x32_bf16(av[i], bv[j], acc[i][j], 0, 0, 0);
#pragma unroll
    for (int i = 0; i < 4; ++i)
#pragma unroll
      for (int j = 0; j < 4; ++j)
        acc[4 + i][j] = __builtin_amdgcn_mfma_f32_16x16x32_bf16(aw[i], bv[j], acc[4 + i][j], 0, 0, 0);
    __builtin_amdgcn_s_setprio(0);
    if (t + 1 < NT) {
      if (t + 2 < NT) { WAITVM(18); } else { WAITVM(0); }   // never 0 mid-loop
      WRITE_B((t + 1) & 1, bqW);
      WAITLGKM;                                             // ds_writes visible pre-barrier
      __builtin_amdgcn_s_barrier();
      __builtin_amdgcn_sched_barrier(0);
    }
  };

  // prologue: A(0),A(1); B(0)->bqA -> LDS; B(1)->bqB in flight
  STAGE_A(0, 0); STAGE_A(1, 32);
  LOAD_B(0, bqA);
  WAITVM(0);
  WRITE_B(0, bqA);
  LOAD_B(1, bqB);
  WAITLGKM;
  __builtin_amdgcn_s_barrier();
  __builtin_amdgcn_sched_barrier(0);

#pragma unroll 1
  for (int tt = 0; tt < NT; tt += 2) {
    TILE(tt, bqA, bqB);        // even: load B(t+2)->bqA (free), write B(t+1) from bqB
    TILE(tt + 1, bqB, bqA);    // odd:  load ->bqB,               write from bqA
  }

  // ---- epilogue: bias+relu+bf16, LDS-coalesced stores (two 128-row halves) ----
  for (int half = 0; half < 2; ++half) {
    __syncthreads();
    if (wm == half) {
#pragma unroll
      for (int i = 0; i < 8; ++i)
#pragma unroll
        for (int j = 0; j < 4; ++j) {
          const int col = wn * 64 + j * 16 + fr;
#pragma unroll
          for (int r = 0; r < 4; ++r) {
            float v = fmaxf(acc[i][j][r] + bvf[j], 0.0f);
            LDS[(i * 16 + fq * 4 + r) * 264 + col] = f2bf(v);
          }
        }
    }
    __syncthreads();
#pragma unroll
    for (int ps = 0; ps < 8; ++ps) {
      int idx = ps * 512 + tid, row = idx >> 5, c = idx & 31;
      u16x8 vv = *(const u16x8*)&LDS[row * 264 + c * 8];
      *(u16x8*)&Hu[(size_t)(m0 + half * 128 + row) * HDIM + n0 + c * 8] = vv;
    }
  }
}

// ---------------- GEMM2: Yu = Hu @ W2 + b2, W2 fp32 [H][C], fp32 out, 256x256 ----------------
__global__ __launch_bounds__(512, 2) void gemm_o_kernel(
    const u16* __restrict__ Hu, const float* __restrict__ W2, const float* __restrict__ RW2,
    const float* __restrict__ sh_b2, const float* __restrict__ rt_b2,
    const int* __restrict__ tile_expert,
    float* __restrict__ Yu) {
  // bijective XCD swizzle: nwg = 4*56 = 224, q = 28
  const int orig = blockIdx.y * 4 + blockIdx.x;
  const int wg = (orig & 7) * 28 + (orig >> 3);
  const int tile = wg >> 2, nidx = wg & 3;
  int e = tile_expert[tile];
  if (e < 0) return;
  const float* Bw = (e == 8) ? W2 : RW2 + (size_t)e * HDIM * CDIM;   // [H][C] fp32
  const float* bias = (e == 8) ? sh_b2 : rt_b2 + e * CDIM;

  __shared__ u16 LDS2[40960];  // 80KB
  u16* As = LDS2;
  u16* Bs = LDS2 + 24576;

  const int tid = threadIdx.x;
  const int l = tid & 63, w = tid >> 6;
  const int wm = w >> 2, wn = w & 3;        // 2M x 4N (wave tile 128x64)
  const int fr = l & 15, fq = l >> 4;
  const int m0 = tile * 256, n0 = nidx * 256;

  const u16* aSrc0 = Hu + (size_t)(m0 + 32 * w + fr) * HDIM + fq * 8;
  const u16* aSrc1 = Hu + (size_t)(m0 + 32 * w + 16 + fr) * HDIM + fq * 8;
  auto STAGE_A = [&](int bi, int kofs) {
    gload16(aSrc0 + kofs, As + bi * 8192 + (2 * w + 0) * 512);
    gload16(aSrc1 + kofs, As + bi * 8192 + (2 * w + 1) * 512);
  };

  const float* bSrc = Bw + (size_t)((l >> 5) * 16) * CDIM + (n0 + 32 * w + (l & 31));
  float bqA[16], bqB[16];
  auto LOAD_B = [&](int kt, float (&bq)[16]) {
    const float* s = bSrc + (size_t)kt * 32 * CDIM;
#pragma unroll
    for (int j = 0; j < 16; ++j) bq[j] = s[(size_t)j * CDIM];
  };
  u16* bBase = Bs + (2 * w + ((l & 31) >> 4)) * 512 + (l & 15) * 8 + (l >> 5) * 256;
  auto WRITE_B = [&](int bi, const float (&bq)[16]) {
    u16x8 v0, v1;
#pragma unroll
    for (int j = 0; j < 8; ++j) { v0[j] = f2bf(bq[j]); v1[j] = f2bf(bq[8 + j]); }
    *(u16x8*)(bBase + bi * 8192) = v0;
    *(u16x8*)(bBase + bi * 8192 + 128) = v1;
  };

  float bvf[4];
#pragma unroll
  for (int j = 0; j < 4; ++j) bvf[j] = bias[n0 + wn * 64 + j * 16 + fr];

  f32x4 acc[8][4] = {};
  const int NT = HDIM / 32;   // 128 (even)

  auto TILE = [&](int t, float (&bqL)[16], float (&bqW)[16]) {
    if (t + 2 < NT) { STAGE_A((t + 2) % 3, (t + 2) * 32); LOAD_B(t + 2, bqL); }
    const u16* ab = As + (t % 3) * 8192 + l * 8;
    const u16* bb = Bs + (t & 1) * 8192 + l * 8;
    bf16x8 av[4], bv[4], aw[4];
#pragma unroll
    for (int j = 0; j < 4; ++j) bv[j] = *(const bf16x8*)&bb[(wn * 4 + j) * 512];
#pragma unroll
    for (int i = 0; i < 4; ++i) av[i] = *(const bf16x8*)&ab[(wm * 8 + i) * 512];
#pragma unroll
    for (int i = 0; i < 4; ++i) aw[i] = *(const bf16x8*)&ab[(wm * 8 + 4 + i) * 512];
    __builtin_amdgcn_s_setprio(1);
#pragma unroll
    for (int i = 0; i < 4; ++i)
#pragma unroll
      for (int j = 0; j < 4; ++j)
        acc[i][j] = __builtin_amdgcn_mfma_f32_16x16x32_bf16(av[i], bv[j], acc[i][j], 0, 0, 0);
#pragma unroll
    for (int i = 0; i < 4; ++i)
#pragma unroll
      for (int j = 0; j < 4; ++j)
        acc[4 + i][j] = __builtin_amdgcn_mfma_f32_16x16x32_bf16(aw[i], bv[j], acc[4 + i][j], 0, 0, 0);
    __builtin_amdgcn_s_setprio(0);
    if (t + 1 < NT) {
      if (t + 2 < NT) { WAITVM(18); } else { WAITVM(0); }
      WRITE_B((t + 1) & 1, bqW);
      WAITLGKM;
      __builtin_amdgcn_s_barrier();
      __builtin_amdgcn_sched_barrier(0);
    }
  };

  STAGE_A(0, 0); STAGE_A(1, 32);
  LOAD_B(0, bqA);
  WAITVM(0);
  WRITE_B(0, bqA);
  LOAD_B(1, bqB);
  WAITLGKM;
  __builtin_amdgcn_s_barrier();
  __builtin_amdgcn_sched_barrier(0);

#pragma unroll 1
  for (int tt = 0; tt < NT; tt += 2) {
    TILE(tt, bqA, bqB);
    TILE(tt + 1, bqB, bqA);
  }

  const size_t mb = m0 + wm * 128;
#pragma unroll
  for (int j = 0; j < 4; ++j) {
    const int n_g = n0 + wn * 64 + j * 16 + fr;
#pragma unroll
    for (int i = 0; i < 8; ++i)
#pragma unroll
      for (int r = 0; r < 4; ++r)
        Yu[(mb + i * 16 + fq * 4 + r) * (size_t)CDIM + n_g] = acc[i][j][r] + bvf[j];
  }
}

// ---------------- combine: out = shared + w0*expert0 + w1*expert1 ----------------
__global__ void combine_kernel(const float* __restrict__ Yu, const float* __restrict__ w01,
                               const int* __restrict__ slot_of, float* __restrict__ out) {
  int gid = blockIdx.x * 256 + threadIdx.x;   // 4096 blocks; 256 float4 per token row
  int t = gid >> 8;
  int c4 = gid & 255;
  int s0 = slot_of[t * 2], s1 = slot_of[t * 2 + 1];
  float wq0 = w01[t * 2], wq1 = w01[t * 2 + 1];
  float4 a  = ((const float4*)(Yu + (size_t)t  * CDIM))[c4];
  float4 b0 = ((const float4*)(Yu + (size_t)s0 * CDIM))[c4];
  float4 b1 = ((const float4*)(Yu + (size_t)s1 * CDIM))[c4];
  float4 rv;
  rv.x = a.x + wq0 * b0.x + wq1 * b1.x;
  rv.y = a.y + wq0 * b0.y + wq1 * b1.y;
  rv.z = a.z + wq0 * b0.z + wq1 * b1.z;
  rv.w = a.w + wq0 * b0.w + wq1 * b1.w;
  ((float4*)out)[gid] = rv;
}

extern "C" void kernel_launch(void* const* d_in, const int* in_sizes, int n_in,
                              void* d_out, int out_size, void* d_ws, size_t ws_size,
                              hipStream_t stream) {
  const float* X        = (const float*)d_in[0];   // [4096,1024]
  const float* router_w = (const float*)d_in[1];   // [1024,8]
  const float* sh_w1    = (const float*)d_in[2];   // [1024,4096]  [C][H]
  const float* sh_b1    = (const float*)d_in[3];   // [4096]
  const float* sh_w2    = (const float*)d_in[4];   // [4096,1024]  [H][C]
  const float* sh_b2    = (const float*)d_in[5];   // [1024]
  const float* rt_w1    = (const float*)d_in[6];   // [8,1024,4096]
  const float* rt_b1    = (const float*)d_in[7];   // [8,4096]
  const float* rt_w2    = (const float*)d_in[8];   // [8,4096,1024]
  const float* rt_b2    = (const float*)d_in[9];   // [8,1024]
  float* out = (float*)d_out;

  // ---- workspace layout ----
  char* p = (char*)d_ws;
  auto take = [&](size_t bytes) { char* q = p; p += (bytes + 255) & ~(size_t)255; return q; };
  u16*  Xb   = (u16*)take((size_t)NTOK * CDIM * 2);        //   8 MB
  u16*  Hu   = (u16*)take((size_t)SLOTS * HDIM * 2);       // 112 MB
  float* Yu  = (float*)take((size_t)SLOTS * CDIM * 4);     //  56 MB
  float* w01 = (float*)take((size_t)NTOK * 2 * 4);
  int*  e01  = (int*)take((size_t)NTOK * 2 * 4);
  int*  slot_of = (int*)take((size_t)NTOK * 2 * 4);
  int*  order   = (int*)take((size_t)SLOTS * 4);
  int*  tile_expert = (int*)take((size_t)NTILES * 4);
  float* pP  = (float*)take((size_t)RBLK * 8 * 4);         //  32 KB router prob partials
  int*  pC   = (int*)take((size_t)RBLK * 8 * 4);           //  32 KB router count partials
  int*  cursor = (int*)take(256);
  int*  roff   = (int*)take(256);
  size_t need = (size_t)(p - (char*)d_ws);
  if (ws_size < need) return;  // insufficient scratch -> fail visibly (poisoned out)

  // ---- pipeline ----
  init_kernel<<<NTILES, 256, 0, stream>>>(order, tile_expert, cursor);
  router_kernel<<<RBLK, 256, 0, stream>>>(X, router_w, Xb, w01, e01, pP, pC);
  setup_kernel<<<1, 256, 0, stream>>>(pP, pC, roff, tile_expert, out + (size_t)NTOK * CDIM);
  scatter_kernel<<<NTOK / 256, 256, 0, stream>>>(e01, roff, cursor, order, slot_of);
  gemm_h_kernel<<<dim3(16, NTILES), 512, 0, stream>>>(
      Xb, sh_w1, rt_w1, sh_b1, rt_b1, tile_expert, order, Hu);
  gemm_o_kernel<<<dim3(4, NTILES), 512, 0, stream>>>(
      Hu, sh_w2, rt_w2, sh_b2, rt_b2, tile_expert, Yu);
  combine_kernel<<<(NTOK * CDIM / 4) / 256, 256, 0, stream>>>(Yu, w01, slot_of, out);
}

// Round 15
// 417.794 us; speedup vs baseline: 1.0226x; 1.0226x over previous
//
#include <hip/hip_runtime.h>

// MoE layer: B=4,T=1024,C=1024,H=4096,E=8, top-2 routing, shared expert.
// Sparse formulation: only top-2 experts per token are computed.
//
// R15 == R13 exactly (415us session-best). R14's deeper B-pipeline (double
// reg buffer, WAITVM(18)) regressed to 427us -- 4th falsified schedule
// micro-iteration on this structure; reverting to the empirical optimum.
// Structure: fused router+bf16-convert, padded per-expert slot lists,
// 256x256-tile MFMA GEMMs (BK=32, A via global_load_lds 3-buf dist-2,
// fp32 weights reg-staged->LDS bf16 2-buf, counted vmcnt(2), one barrier
// per K-tile, conflict-free lane-major LDS, XCD swizzles, setprio,
// LDS-coalesced bf16 epilogue), weighted combine.

typedef unsigned short u16;
typedef __bf16 bf16x8 __attribute__((ext_vector_type(8)));
typedef float f32x4 __attribute__((ext_vector_type(4)));
typedef u16 u16x8 __attribute__((ext_vector_type(8)));

#define NTOK 4096
#define CDIM 1024
#define HDIM 4096
#define NEXP 8
#define SLOTS 14336   // 4096 shared (16 tiles) + 10240 routed capacity (256-aligned segs)
#define NTILES 56     // SLOTS/256
#define RBLK 1024     // router grid (4 tokens/block)

#define WAITVM(N) do { asm volatile("s_waitcnt vmcnt(" #N ")" ::: "memory"); } while (0)
#define WAITLGKM do { asm volatile("s_waitcnt lgkmcnt(0)" ::: "memory"); } while (0)

static __device__ __forceinline__ u16 f2bf(float f) {   // round-to-nearest-even
  unsigned u = __float_as_uint(f);
  u += 0x7fffu + ((u >> 16) & 1u);
  return (u16)(u >> 16);
}

static __device__ __forceinline__ void gload16(const void* g, void* l) {
  __builtin_amdgcn_global_load_lds((const __attribute__((address_space(1))) unsigned int*)g,
                                   (__attribute__((address_space(3))) unsigned int*)l,
                                   16, 0, 0);
}

// ---------------- init: zero cursor, identity/pad slot map ----------------
__global__ void init_kernel(int* order, int* tile_expert, int* cursor) {
  int i = blockIdx.x * 256 + threadIdx.x;      // grid 56*256 = 14336
  if (i < SLOTS) order[i] = (i < NTOK) ? i : -1;
  if (i < NTILES) tile_expert[i] = (i < 16) ? 8 : -1;   // tiles 0..15 = shared expert
  if (i < NEXP) cursor[i] = 0;
}

// ---------------- router + X->bf16 fused: 1 wave/token, NO global atomics ----------------
__global__ __launch_bounds__(256) void router_kernel(
    const float* __restrict__ X, const float* __restrict__ rw,
    u16* __restrict__ Xb,
    float* __restrict__ w01, int* __restrict__ e01,
    float* __restrict__ pP, int* __restrict__ pC) {
  __shared__ float wP[4][8];
  __shared__ int wE[4][2];
  const int tid = threadIdx.x;
  const int w = tid >> 6, l = tid & 63;
  const int wid = blockIdx.x * 4 + w;   // token
  const float* x = X + (size_t)wid * CDIM;
  u16* xbrow = Xb + (size_t)wid * CDIM;
  float s[8] = {0.f,0.f,0.f,0.f,0.f,0.f,0.f,0.f};
#pragma unroll 4
  for (int i = 0; i < 16; ++i) {
    int c = i * 64 + l;
    float xv = x[c];
    xbrow[c] = f2bf(xv);                // fused bf16 conversion (was xconv)
    const float4* rp = (const float4*)(rw + c * 8);
    float4 r0 = rp[0], r1 = rp[1];
    s[0] += xv * r0.x; s[1] += xv * r0.y; s[2] += xv * r0.z; s[3] += xv * r0.w;
    s[4] += xv * r1.x; s[5] += xv * r1.y; s[6] += xv * r1.z; s[7] += xv * r1.w;
  }
#pragma unroll
  for (int off = 32; off; off >>= 1)
#pragma unroll
    for (int e = 0; e < 8; ++e) s[e] += __shfl_down(s[e], off);
  if (l == 0) {
    float m = s[0];
#pragma unroll
    for (int e = 1; e < 8; ++e) m = fmaxf(m, s[e]);
    float p[8], d = 0.f;
#pragma unroll
    for (int e = 0; e < 8; ++e) { p[e] = expf(s[e] - m); d += p[e]; }
    float inv = 1.f / d;
#pragma unroll
    for (int e = 0; e < 8; ++e) p[e] *= inv;
    int e0 = 0;
#pragma unroll
    for (int e = 1; e < 8; ++e) if (p[e] > p[e0]) e0 = e;   // ties -> lowest idx (jax)
    int e1 = -1;
#pragma unroll
    for (int e = 0; e < 8; ++e) if (e != e0 && (e1 < 0 || p[e] > p[e1])) e1 = e;
    w01[wid * 2] = p[e0]; w01[wid * 2 + 1] = p[e1];
    e01[wid * 2] = e0;    e01[wid * 2 + 1] = e1;
#pragma unroll
    for (int e = 0; e < 8; ++e) wP[w][e] = p[e];
    wE[w][0] = e0; wE[w][1] = e1;
  }
  __syncthreads();
  if (tid < 8) {
    pP[blockIdx.x * 8 + tid] = wP[0][tid] + wP[1][tid] + wP[2][tid] + wP[3][tid];
    int c = 0;
#pragma unroll
    for (int v = 0; v < 4; ++v) c += (wE[v][0] == tid) + (wE[v][1] == tid);
    pC[blockIdx.x * 8 + tid] = c;
  }
}

// ---------------- setup: reduce partials, offsets (256-aligned), tile map, aux ----------------
__global__ __launch_bounds__(256) void setup_kernel(
    const float* __restrict__ pP, const int* __restrict__ pC,
    int* __restrict__ roff, int* __restrict__ tile_expert, float* __restrict__ out_aux) {
  __shared__ float sP[32][8];
  __shared__ int   sC[32][8];
  const int tid = threadIdx.x;
  const int e = tid & 7, g = tid >> 3;   // 32 groups x 8 experts
  float fs = 0.f; int cs = 0;
  for (int b = g; b < RBLK; b += 32) { fs += pP[b * 8 + e]; cs += pC[b * 8 + e]; }
  sP[g][e] = fs; sC[g][e] = cs;
  __syncthreads();
  if (tid == 0) {
    float P[8]; int C[8];
    for (int e2 = 0; e2 < 8; ++e2) {
      float f2 = 0.f; int c2 = 0;
      for (int g2 = 0; g2 < 32; ++g2) { f2 += sP[g2][e2]; c2 += sC[g2][e2]; }
      P[e2] = f2; C[e2] = c2;
    }
    int off = NTOK;
    float a = 0.f;
    for (int e2 = 0; e2 < NEXP; ++e2) {
      roff[e2] = off;
      int nt = (C[e2] + 255) >> 8;
      int t0 = off >> 8;
      for (int i = 0; i < nt; ++i) tile_expert[t0 + i] = e2;
      off += nt << 8;
      a += (C[e2] * (1.f / NTOK)) * (P[e2] * (1.f / NTOK));
    }
    out_aux[0] = (float)NEXP * a;
  }
}

// ---------------- scatter: token -> slots, block-aggregated cursor ----------------
__global__ __launch_bounds__(256) void scatter_kernel(
    const int* __restrict__ e01, const int* __restrict__ roff,
    int* __restrict__ cursor, int* __restrict__ order, int* __restrict__ slot_of) {
  __shared__ int cnt_l[8];
  __shared__ int base_l[8];
  const int tid = threadIdx.x;
  const int t = blockIdx.x * 256 + tid;   // grid 16 blocks
  if (tid < 8) cnt_l[tid] = 0;
  __syncthreads();
  int e0 = e01[t * 2], e1 = e01[t * 2 + 1];
  int p0 = atomicAdd(&cnt_l[e0], 1);      // LDS atomics
  int p1 = atomicAdd(&cnt_l[e1], 1);
  __syncthreads();
  if (tid < 8) base_l[tid] = atomicAdd(&cursor[tid], cnt_l[tid]);  // 8 global atomics/block
  __syncthreads();
  int s0 = roff[e0] + base_l[e0] + p0;
  int s1 = roff[e1] + base_l[e1] + p1;
  order[s0] = t; order[s1] = t;
  slot_of[t * 2] = s0; slot_of[t * 2 + 1] = s1;
}

// LDS layout (both GEMMs): per 256x32 operand K-tile, 1KB chunks. Chunk g =
// rows 16g..16g+15; slot l = (row 16g+(l&15), k (l>>4)*8..+7). A staged by
// gload16 (3 bufs, distance 2); B staged via regs: lane l loads 16 fp32
// (k = kt*32+(l>>5)*16+j, n = n0+32w+(l&31)), converts, writes 2 b128 into
// chunk c = 2w+((l&31)>>4), slots ((l>>5)*2+h)<<4 | (l&15). All LDS ops
// wave-uniform-base + disjoint 16B slots -> zero bank conflicts.

// ---------------- GEMM1: hidden = relu(A @ W1 + b1), W1 fp32 [C][H], out bf16 ----------------
__global__ __launch_bounds__(512, 2) void gemm_h_kernel(
    const u16* __restrict__ Xb, const float* __restrict__ W1, const float* __restrict__ RW1,
    const float* __restrict__ sh_b1, const float* __restrict__ rt_b1,
    const int* __restrict__ tile_expert, const int* __restrict__ order,
    u16* __restrict__ Hu) {
  // bijective XCD swizzle, TILE-FAST decode: nwg = 896 = 8 XCD x 112;
  // consecutive wg -> consecutive tiles at same nidx (B-panel L2 reuse).
  const int orig = blockIdx.y * 16 + blockIdx.x;
  const int wg = (orig & 7) * 112 + (orig >> 3);
  const int tile = wg % 56, nidx = wg / 56;
  int e = tile_expert[tile];
  if (e < 0) return;
  const float* Bw = (e == 8) ? W1 : RW1 + (size_t)e * CDIM * HDIM;   // [C][H] fp32
  const float* bias = (e == 8) ? sh_b1 : rt_b1 + e * HDIM;

  __shared__ u16 LDS[40960];   // 80KB: A 3x8192 + B 2x8192; epilogue [128][264]
  u16* As = LDS;
  u16* Bs = LDS + 24576;

  const int tid = threadIdx.x;
  const int l = tid & 63, w = tid >> 6;     // 8 waves
  const int wm = w >> 2, wn = w & 3;        // 2M x 4N (wave tile 128x64)
  const int fr = l & 15, fq = l >> 4;
  const int m0 = tile * 256, n0 = nidx * 256;

  int tok0 = order[m0 + 32 * w + fr];      if (tok0 < 0) tok0 = 0;
  int tok1 = order[m0 + 32 * w + 16 + fr]; if (tok1 < 0) tok1 = 0;
  const u16* aSrc0 = Xb + (size_t)tok0 * CDIM + fq * 8;
  const u16* aSrc1 = Xb + (size_t)tok1 * CDIM + fq * 8;
  auto STAGE_A = [&](int bi, int kofs) {
    gload16(aSrc0 + kofs, As + bi * 8192 + (2 * w + 0) * 512);
    gload16(aSrc1 + kofs, As + bi * 8192 + (2 * w + 1) * 512);
  };

  // B: fp32 [CDIM][HDIM]; lane covers n = n0+32w+(l&31), k base (l>>5)*16
  const float* bSrc = Bw + (size_t)((l >> 5) * 16) * HDIM + (n0 + 32 * w + (l & 31));
  float bq[16];
  auto LOAD_B = [&](int kt) {
    const float* s = bSrc + (size_t)kt * 32 * HDIM;
#pragma unroll
    for (int j = 0; j < 16; ++j) bq[j] = s[(size_t)j * HDIM];
  };
  u16* bBase = Bs + (2 * w + ((l & 31) >> 4)) * 512 + (l & 15) * 8 + (l >> 5) * 256;
  auto WRITE_B = [&](int bi) {
    u16x8 v0, v1;
#pragma unroll
    for (int j = 0; j < 8; ++j) { v0[j] = f2bf(bq[j]); v1[j] = f2bf(bq[8 + j]); }
    *(u16x8*)(bBase + bi * 8192) = v0;
    *(u16x8*)(bBase + bi * 8192 + 128) = v1;
  };

  float bvf[4];
#pragma unroll
  for (int j = 0; j < 4; ++j) bvf[j] = bias[n0 + wn * 64 + j * 16 + fr];

  f32x4 acc[8][4] = {};
  const int NT = CDIM / 32;   // 32
  // prologue: A(0),A(1) gloads; B(0) regs -> drain -> LDS; B(1) regs in flight
  STAGE_A(0, 0); STAGE_A(1, 32);
  LOAD_B(0);
  WAITVM(0);
  WRITE_B(0);
  LOAD_B(1);
  WAITLGKM;
  __builtin_amdgcn_s_barrier();
  __builtin_amdgcn_sched_barrier(0);

#pragma unroll 1
  for (int t = 0; t < NT; ++t) {
    if (t + 2 < NT) STAGE_A((t + 2) % 3, (t + 2) * 32);
    const u16* ab = As + (t % 3) * 8192 + l * 8;
    const u16* bb = Bs + (t & 1) * 8192 + l * 8;
    bf16x8 av[4], bv[4], aw[4];
#pragma unroll
    for (int j = 0; j < 4; ++j) bv[j] = *(const bf16x8*)&bb[(wn * 4 + j) * 512];
#pragma unroll
    for (int i = 0; i < 4; ++i) av[i] = *(const bf16x8*)&ab[(wm * 8 + i) * 512];
#pragma unroll
    for (int i = 0; i < 4; ++i) aw[i] = *(const bf16x8*)&ab[(wm * 8 + 4 + i) * 512];
    __builtin_amdgcn_s_setprio(1);
#pragma unroll
    for (int i = 0; i < 4; ++i)
#pragma unroll
      for (int j = 0; j < 4; ++j)
        acc[i][j] = __builtin_amdgcn_mfma_f32_16x16x32_bf16(av[i], bv[j], acc[i][j], 0, 0, 0);
#pragma unroll
    for (int i = 0; i < 4; ++i)
#pragma unroll
      for (int j = 0; j < 4; ++j)
        acc[4 + i][j] = __builtin_amdgcn_mfma_f32_16x16x32_bf16(aw[i], bv[j], acc[4 + i][j], 0, 0, 0);
    __builtin_amdgcn_s_setprio(0);
    if (t + 1 < NT) {
      if (t + 2 < NT) { WAITVM(2); } else { WAITVM(0); }   // drain Bl(t+1); A(t+2) stays
      WRITE_B((t + 1) & 1);
      if (t + 2 < NT) LOAD_B(t + 2);
      WAITLGKM;                                            // ds_writes visible pre-barrier
      __builtin_amdgcn_s_barrier();
      __builtin_amdgcn_sched_barrier(0);
    }
  }

  // ---- epilogue: bias+relu+bf16, LDS-coalesced stores (two 128-row halves) ----
  for (int half = 0; half < 2; ++half) {
    __syncthreads();
    if (wm == half) {
#pragma unroll
      for (int i = 0; i < 8; ++i)
#pragma unroll
        for (int j = 0; j < 4; ++j) {
          const int col = wn * 64 + j * 16 + fr;
#pragma unroll
          for (int r = 0; r < 4; ++r) {
            float v = fmaxf(acc[i][j][r] + bvf[j], 0.0f);
            LDS[(i * 16 + fq * 4 + r) * 264 + col] = f2bf(v);
          }
        }
    }
    __syncthreads();
#pragma unroll
    for (int ps = 0; ps < 8; ++ps) {
      int idx = ps * 512 + tid, row = idx >> 5, c = idx & 31;
      u16x8 vv = *(const u16x8*)&LDS[row * 264 + c * 8];
      *(u16x8*)&Hu[(size_t)(m0 + half * 128 + row) * HDIM + n0 + c * 8] = vv;
    }
  }
}

// ---------------- GEMM2: Yu = Hu @ W2 + b2, W2 fp32 [H][C], fp32 out, 256x256 ----------------
__global__ __launch_bounds__(512, 2) void gemm_o_kernel(
    const u16* __restrict__ Hu, const float* __restrict__ W2, const float* __restrict__ RW2,
    const float* __restrict__ sh_b2, const float* __restrict__ rt_b2,
    const int* __restrict__ tile_expert,
    float* __restrict__ Yu) {
  // bijective XCD swizzle: nwg = 4*56 = 224, q = 28
  const int orig = blockIdx.y * 4 + blockIdx.x;
  const int wg = (orig & 7) * 28 + (orig >> 3);
  const int tile = wg >> 2, nidx = wg & 3;
  int e = tile_expert[tile];
  if (e < 0) return;
  const float* Bw = (e == 8) ? W2 : RW2 + (size_t)e * HDIM * CDIM;   // [H][C] fp32
  const float* bias = (e == 8) ? sh_b2 : rt_b2 + e * CDIM;

  __shared__ u16 LDS2[40960];  // 80KB
  u16* As = LDS2;
  u16* Bs = LDS2 + 24576;

  const int tid = threadIdx.x;
  const int l = tid & 63, w = tid >> 6;
  const int wm = w >> 2, wn = w & 3;        // 2M x 4N (wave tile 128x64)
  const int fr = l & 15, fq = l >> 4;
  const int m0 = tile * 256, n0 = nidx * 256;

  const u16* aSrc0 = Hu + (size_t)(m0 + 32 * w + fr) * HDIM + fq * 8;
  const u16* aSrc1 = Hu + (size_t)(m0 + 32 * w + 16 + fr) * HDIM + fq * 8;
  auto STAGE_A = [&](int bi, int kofs) {
    gload16(aSrc0 + kofs, As + bi * 8192 + (2 * w + 0) * 512);
    gload16(aSrc1 + kofs, As + bi * 8192 + (2 * w + 1) * 512);
  };

  const float* bSrc = Bw + (size_t)((l >> 5) * 16) * CDIM + (n0 + 32 * w + (l & 31));
  float bq[16];
  auto LOAD_B = [&](int kt) {
    const float* s = bSrc + (size_t)kt * 32 * CDIM;
#pragma unroll
    for (int j = 0; j < 16; ++j) bq[j] = s[(size_t)j * CDIM];
  };
  u16* bBase = Bs + (2 * w + ((l & 31) >> 4)) * 512 + (l & 15) * 8 + (l >> 5) * 256;
  auto WRITE_B = [&](int bi) {
    u16x8 v0, v1;
#pragma unroll
    for (int j = 0; j < 8; ++j) { v0[j] = f2bf(bq[j]); v1[j] = f2bf(bq[8 + j]); }
    *(u16x8*)(bBase + bi * 8192) = v0;
    *(u16x8*)(bBase + bi * 8192 + 128) = v1;
  };

  float bvf[4];
#pragma unroll
  for (int j = 0; j < 4; ++j) bvf[j] = bias[n0 + wn * 64 + j * 16 + fr];

  f32x4 acc[8][4] = {};
  const int NT = HDIM / 32;   // 128
  STAGE_A(0, 0); STAGE_A(1, 32);
  LOAD_B(0);
  WAITVM(0);
  WRITE_B(0);
  LOAD_B(1);
  WAITLGKM;
  __builtin_amdgcn_s_barrier();
  __builtin_amdgcn_sched_barrier(0);

#pragma unroll 1
  for (int t = 0; t < NT; ++t) {
    if (t + 2 < NT) STAGE_A((t + 2) % 3, (t + 2) * 32);
    const u16* ab = As + (t % 3) * 8192 + l * 8;
    const u16* bb = Bs + (t & 1) * 8192 + l * 8;
    bf16x8 av[4], bv[4], aw[4];
#pragma unroll
    for (int j = 0; j < 4; ++j) bv[j] = *(const bf16x8*)&bb[(wn * 4 + j) * 512];
#pragma unroll
    for (int i = 0; i < 4; ++i) av[i] = *(const bf16x8*)&ab[(wm * 8 + i) * 512];
#pragma unroll
    for (int i = 0; i < 4; ++i) aw[i] = *(const bf16x8*)&ab[(wm * 8 + 4 + i) * 512];
    __builtin_amdgcn_s_setprio(1);
#pragma unroll
    for (int i = 0; i < 4; ++i)
#pragma unroll
      for (int j = 0; j < 4; ++j)
        acc[i][j] = __builtin_amdgcn_mfma_f32_16x16x32_bf16(av[i], bv[j], acc[i][j], 0, 0, 0);
#pragma unroll
    for (int i = 0; i < 4; ++i)
#pragma unroll
      for (int j = 0; j < 4; ++j)
        acc[4 + i][j] = __builtin_amdgcn_mfma_f32_16x16x32_bf16(aw[i], bv[j], acc[4 + i][j], 0, 0, 0);
    __builtin_amdgcn_s_setprio(0);
    if (t + 1 < NT) {
      if (t + 2 < NT) { WAITVM(2); } else { WAITVM(0); }
      WRITE_B((t + 1) & 1);
      if (t + 2 < NT) LOAD_B(t + 2);
      WAITLGKM;
      __builtin_amdgcn_s_barrier();
      __builtin_amdgcn_sched_barrier(0);
    }
  }

  const size_t mb = m0 + wm * 128;
#pragma unroll
  for (int j = 0; j < 4; ++j) {
    const int n_g = n0 + wn * 64 + j * 16 + fr;
#pragma unroll
    for (int i = 0; i < 8; ++i)
#pragma unroll
      for (int r = 0; r < 4; ++r)
        Yu[(mb + i * 16 + fq * 4 + r) * (size_t)CDIM + n_g] = acc[i][j][r] + bvf[j];
  }
}

// ---------------- combine: out = shared + w0*expert0 + w1*expert1 ----------------
__global__ void combine_kernel(const float* __restrict__ Yu, const float* __restrict__ w01,
                               const int* __restrict__ slot_of, float* __restrict__ out) {
  int gid = blockIdx.x * 256 + threadIdx.x;   // 4096 blocks; 256 float4 per token row
  int t = gid >> 8;
  int c4 = gid & 255;
  int s0 = slot_of[t * 2], s1 = slot_of[t * 2 + 1];
  float wq0 = w01[t * 2], wq1 = w01[t * 2 + 1];
  float4 a  = ((const float4*)(Yu + (size_t)t  * CDIM))[c4];
  float4 b0 = ((const float4*)(Yu + (size_t)s0 * CDIM))[c4];
  float4 b1 = ((const float4*)(Yu + (size_t)s1 * CDIM))[c4];
  float4 rv;
  rv.x = a.x + wq0 * b0.x + wq1 * b1.x;
  rv.y = a.y + wq0 * b0.y + wq1 * b1.y;
  rv.z = a.z + wq0 * b0.z + wq1 * b1.z;
  rv.w = a.w + wq0 * b0.w + wq1 * b1.w;
  ((float4*)out)[gid] = rv;
}

extern "C" void kernel_launch(void* const* d_in, const int* in_sizes, int n_in,
                              void* d_out, int out_size, void* d_ws, size_t ws_size,
                              hipStream_t stream) {
  const float* X        = (const float*)d_in[0];   // [4096,1024]
  const float* router_w = (const float*)d_in[1];   // [1024,8]
  const float* sh_w1    = (const float*)d_in[2];   // [1024,4096]  [C][H]
  const float* sh_b1    = (const float*)d_in[3];   // [4096]
  const float* sh_w2    = (const float*)d_in[4];   // [4096,1024]  [H][C]
  const float* sh_b2    = (const float*)d_in[5];   // [1024]
  const float* rt_w1    = (const float*)d_in[6];   // [8,1024,4096]
  const float* rt_b1    = (const float*)d_in[7];   // [8,4096]
  const float* rt_w2    = (const float*)d_in[8];   // [8,4096,1024]
  const float* rt_b2    = (const float*)d_in[9];   // [8,1024]
  float* out = (float*)d_out;

  // ---- workspace layout ----
  char* p = (char*)d_ws;
  auto take = [&](size_t bytes) { char* q = p; p += (bytes + 255) & ~(size_t)255; return q; };
  u16*  Xb   = (u16*)take((size_t)NTOK * CDIM * 2);        //   8 MB
  u16*  Hu   = (u16*)take((size_t)SLOTS * HDIM * 2);       // 112 MB
  float* Yu  = (float*)take((size_t)SLOTS * CDIM * 4);     //  56 MB
  float* w01 = (float*)take((size_t)NTOK * 2 * 4);
  int*  e01  = (int*)take((size_t)NTOK * 2 * 4);
  int*  slot_of = (int*)take((size_t)NTOK * 2 * 4);
  int*  order   = (int*)take((size_t)SLOTS * 4);
  int*  tile_expert = (int*)take((size_t)NTILES * 4);
  float* pP  = (float*)take((size_t)RBLK * 8 * 4);         //  32 KB router prob partials
  int*  pC   = (int*)take((size_t)RBLK * 8 * 4);           //  32 KB router count partials
  int*  cursor = (int*)take(256);
  int*  roff   = (int*)take(256);
  size_t need = (size_t)(p - (char*)d_ws);
  if (ws_size < need) return;  // insufficient scratch -> fail visibly (poisoned out)

  // ---- pipeline ----
  init_kernel<<<NTILES, 256, 0, stream>>>(order, tile_expert, cursor);
  router_kernel<<<RBLK, 256, 0, stream>>>(X, router_w, Xb, w01, e01, pP, pC);
  setup_kernel<<<1, 256, 0, stream>>>(pP, pC, roff, tile_expert, out + (size_t)NTOK * CDIM);
  scatter_kernel<<<NTOK / 256, 256, 0, stream>>>(e01, roff, cursor, order, slot_of);
  gemm_h_kernel<<<dim3(16, NTILES), 512, 0, stream>>>(
      Xb, sh_w1, rt_w1, sh_b1, rt_b1, tile_expert, order, Hu);
  gemm_o_kernel<<<dim3(4, NTILES), 512, 0, stream>>>(
      Hu, sh_w2, rt_w2, sh_b2, rt_b2, tile_expert, Yu);
  combine_kernel<<<(NTOK * CDIM / 4) / 256, 256, 0, stream>>>(Yu, w01, slot_of, out);
}

// Round 16
// 393.611 us; speedup vs baseline: 1.0855x; 1.0614x over previous
//
#include <hip/hip_runtime.h>

// MoE layer: B=4,T=1024,C=1024,H=4096,E=8, top-2 routing, shared expert.
// Sparse formulation: only top-2 experts per token are computed.
//
// R16 = R15 (417us, session-best structure) with ONE change: f2bf is now a
// native (__bf16) cast instead of a 4-op integer bit-twiddle. Lets clang
// emit paired v_cvt_pk_bf16_f32 (1 op per 2 floats; HW RNE == old RNE,
// bit-identical results) -- the B-path spent ~64 VALU ops/tile/lane on
// conversion with VALUBusy at 23.5%. m240 lesson: compiler handles cvt
// best when given the cast, not hand-written bit math.

typedef unsigned short u16;
typedef __bf16 bf16x8 __attribute__((ext_vector_type(8)));
typedef float f32x4 __attribute__((ext_vector_type(4)));
typedef u16 u16x8 __attribute__((ext_vector_type(8)));

#define NTOK 4096
#define CDIM 1024
#define HDIM 4096
#define NEXP 8
#define SLOTS 14336   // 4096 shared (16 tiles) + 10240 routed capacity (256-aligned segs)
#define NTILES 56     // SLOTS/256
#define RBLK 1024     // router grid (4 tokens/block)

#define WAITVM(N) do { asm volatile("s_waitcnt vmcnt(" #N ")" ::: "memory"); } while (0)
#define WAITLGKM do { asm volatile("s_waitcnt lgkmcnt(0)" ::: "memory"); } while (0)

static __device__ __forceinline__ u16 f2bf(float f) {   // native cast -> v_cvt_pk_bf16_f32 (RNE)
  union { __bf16 h; u16 u; } cv;
  cv.h = (__bf16)f;
  return cv.u;
}

static __device__ __forceinline__ void gload16(const void* g, void* l) {
  __builtin_amdgcn_global_load_lds((const __attribute__((address_space(1))) unsigned int*)g,
                                   (__attribute__((address_space(3))) unsigned int*)l,
                                   16, 0, 0);
}

// ---------------- init: zero cursor, identity/pad slot map ----------------
__global__ void init_kernel(int* order, int* tile_expert, int* cursor) {
  int i = blockIdx.x * 256 + threadIdx.x;      // grid 56*256 = 14336
  if (i < SLOTS) order[i] = (i < NTOK) ? i : -1;
  if (i < NTILES) tile_expert[i] = (i < 16) ? 8 : -1;   // tiles 0..15 = shared expert
  if (i < NEXP) cursor[i] = 0;
}

// ---------------- router + X->bf16 fused: 1 wave/token, NO global atomics ----------------
__global__ __launch_bounds__(256) void router_kernel(
    const float* __restrict__ X, const float* __restrict__ rw,
    u16* __restrict__ Xb,
    float* __restrict__ w01, int* __restrict__ e01,
    float* __restrict__ pP, int* __restrict__ pC) {
  __shared__ float wP[4][8];
  __shared__ int wE[4][2];
  const int tid = threadIdx.x;
  const int w = tid >> 6, l = tid & 63;
  const int wid = blockIdx.x * 4 + w;   // token
  const float* x = X + (size_t)wid * CDIM;
  u16* xbrow = Xb + (size_t)wid * CDIM;
  float s[8] = {0.f,0.f,0.f,0.f,0.f,0.f,0.f,0.f};
#pragma unroll 4
  for (int i = 0; i < 16; ++i) {
    int c = i * 64 + l;
    float xv = x[c];
    xbrow[c] = f2bf(xv);                // fused bf16 conversion
    const float4* rp = (const float4*)(rw + c * 8);
    float4 r0 = rp[0], r1 = rp[1];
    s[0] += xv * r0.x; s[1] += xv * r0.y; s[2] += xv * r0.z; s[3] += xv * r0.w;
    s[4] += xv * r1.x; s[5] += xv * r1.y; s[6] += xv * r1.z; s[7] += xv * r1.w;
  }
#pragma unroll
  for (int off = 32; off; off >>= 1)
#pragma unroll
    for (int e = 0; e < 8; ++e) s[e] += __shfl_down(s[e], off);
  if (l == 0) {
    float m = s[0];
#pragma unroll
    for (int e = 1; e < 8; ++e) m = fmaxf(m, s[e]);
    float p[8], d = 0.f;
#pragma unroll
    for (int e = 0; e < 8; ++e) { p[e] = expf(s[e] - m); d += p[e]; }
    float inv = 1.f / d;
#pragma unroll
    for (int e = 0; e < 8; ++e) p[e] *= inv;
    int e0 = 0;
#pragma unroll
    for (int e = 1; e < 8; ++e) if (p[e] > p[e0]) e0 = e;   // ties -> lowest idx (jax)
    int e1 = -1;
#pragma unroll
    for (int e = 0; e < 8; ++e) if (e != e0 && (e1 < 0 || p[e] > p[e1])) e1 = e;
    w01[wid * 2] = p[e0]; w01[wid * 2 + 1] = p[e1];
    e01[wid * 2] = e0;    e01[wid * 2 + 1] = e1;
#pragma unroll
    for (int e = 0; e < 8; ++e) wP[w][e] = p[e];
    wE[w][0] = e0; wE[w][1] = e1;
  }
  __syncthreads();
  if (tid < 8) {
    pP[blockIdx.x * 8 + tid] = wP[0][tid] + wP[1][tid] + wP[2][tid] + wP[3][tid];
    int c = 0;
#pragma unroll
    for (int v = 0; v < 4; ++v) c += (wE[v][0] == tid) + (wE[v][1] == tid);
    pC[blockIdx.x * 8 + tid] = c;
  }
}

// ---------------- setup: reduce partials, offsets (256-aligned), tile map, aux ----------------
__global__ __launch_bounds__(256) void setup_kernel(
    const float* __restrict__ pP, const int* __restrict__ pC,
    int* __restrict__ roff, int* __restrict__ tile_expert, float* __restrict__ out_aux) {
  __shared__ float sP[32][8];
  __shared__ int   sC[32][8];
  const int tid = threadIdx.x;
  const int e = tid & 7, g = tid >> 3;   // 32 groups x 8 experts
  float fs = 0.f; int cs = 0;
  for (int b = g; b < RBLK; b += 32) { fs += pP[b * 8 + e]; cs += pC[b * 8 + e]; }
  sP[g][e] = fs; sC[g][e] = cs;
  __syncthreads();
  if (tid == 0) {
    float P[8]; int C[8];
    for (int e2 = 0; e2 < 8; ++e2) {
      float f2 = 0.f; int c2 = 0;
      for (int g2 = 0; g2 < 32; ++g2) { f2 += sP[g2][e2]; c2 += sC[g2][e2]; }
      P[e2] = f2; C[e2] = c2;
    }
    int off = NTOK;
    float a = 0.f;
    for (int e2 = 0; e2 < NEXP; ++e2) {
      roff[e2] = off;
      int nt = (C[e2] + 255) >> 8;
      int t0 = off >> 8;
      for (int i = 0; i < nt; ++i) tile_expert[t0 + i] = e2;
      off += nt << 8;
      a += (C[e2] * (1.f / NTOK)) * (P[e2] * (1.f / NTOK));
    }
    out_aux[0] = (float)NEXP * a;
  }
}

// ---------------- scatter: token -> slots, block-aggregated cursor ----------------
__global__ __launch_bounds__(256) void scatter_kernel(
    const int* __restrict__ e01, const int* __restrict__ roff,
    int* __restrict__ cursor, int* __restrict__ order, int* __restrict__ slot_of) {
  __shared__ int cnt_l[8];
  __shared__ int base_l[8];
  const int tid = threadIdx.x;
  const int t = blockIdx.x * 256 + tid;   // grid 16 blocks
  if (tid < 8) cnt_l[tid] = 0;
  __syncthreads();
  int e0 = e01[t * 2], e1 = e01[t * 2 + 1];
  int p0 = atomicAdd(&cnt_l[e0], 1);      // LDS atomics
  int p1 = atomicAdd(&cnt_l[e1], 1);
  __syncthreads();
  if (tid < 8) base_l[tid] = atomicAdd(&cursor[tid], cnt_l[tid]);  // 8 global atomics/block
  __syncthreads();
  int s0 = roff[e0] + base_l[e0] + p0;
  int s1 = roff[e1] + base_l[e1] + p1;
  order[s0] = t; order[s1] = t;
  slot_of[t * 2] = s0; slot_of[t * 2 + 1] = s1;
}

// LDS layout (both GEMMs): per 256x32 operand K-tile, 1KB chunks. Chunk g =
// rows 16g..16g+15; slot l = (row 16g+(l&15), k (l>>4)*8..+7). A staged by
// gload16 (3 bufs, distance 2); B staged via regs: lane l loads 16 fp32
// (k = kt*32+(l>>5)*16+j, n = n0+32w+(l&31)), converts, writes 2 b128 into
// chunk c = 2w+((l&31)>>4), slots ((l>>5)*2+h)<<4 | (l&15). All LDS ops
// wave-uniform-base + disjoint 16B slots -> zero bank conflicts.

// ---------------- GEMM1: hidden = relu(A @ W1 + b1), W1 fp32 [C][H], out bf16 ----------------
__global__ __launch_bounds__(512, 2) void gemm_h_kernel(
    const u16* __restrict__ Xb, const float* __restrict__ W1, const float* __restrict__ RW1,
    const float* __restrict__ sh_b1, const float* __restrict__ rt_b1,
    const int* __restrict__ tile_expert, const int* __restrict__ order,
    u16* __restrict__ Hu) {
  // bijective XCD swizzle, TILE-FAST decode: nwg = 896 = 8 XCD x 112;
  // consecutive wg -> consecutive tiles at same nidx (B-panel L2 reuse).
  const int orig = blockIdx.y * 16 + blockIdx.x;
  const int wg = (orig & 7) * 112 + (orig >> 3);
  const int tile = wg % 56, nidx = wg / 56;
  int e = tile_expert[tile];
  if (e < 0) return;
  const float* Bw = (e == 8) ? W1 : RW1 + (size_t)e * CDIM * HDIM;   // [C][H] fp32
  const float* bias = (e == 8) ? sh_b1 : rt_b1 + e * HDIM;

  __shared__ u16 LDS[40960];   // 80KB: A 3x8192 + B 2x8192; epilogue [128][264]
  u16* As = LDS;
  u16* Bs = LDS + 24576;

  const int tid = threadIdx.x;
  const int l = tid & 63, w = tid >> 6;     // 8 waves
  const int wm = w >> 2, wn = w & 3;        // 2M x 4N (wave tile 128x64)
  const int fr = l & 15, fq = l >> 4;
  const int m0 = tile * 256, n0 = nidx * 256;

  int tok0 = order[m0 + 32 * w + fr];      if (tok0 < 0) tok0 = 0;
  int tok1 = order[m0 + 32 * w + 16 + fr]; if (tok1 < 0) tok1 = 0;
  const u16* aSrc0 = Xb + (size_t)tok0 * CDIM + fq * 8;
  const u16* aSrc1 = Xb + (size_t)tok1 * CDIM + fq * 8;
  auto STAGE_A = [&](int bi, int kofs) {
    gload16(aSrc0 + kofs, As + bi * 8192 + (2 * w + 0) * 512);
    gload16(aSrc1 + kofs, As + bi * 8192 + (2 * w + 1) * 512);
  };

  // B: fp32 [CDIM][HDIM]; lane covers n = n0+32w+(l&31), k base (l>>5)*16
  const float* bSrc = Bw + (size_t)((l >> 5) * 16) * HDIM + (n0 + 32 * w + (l & 31));
  float bq[16];
  auto LOAD_B = [&](int kt) {
    const float* s = bSrc + (size_t)kt * 32 * HDIM;
#pragma unroll
    for (int j = 0; j < 16; ++j) bq[j] = s[(size_t)j * HDIM];
  };
  u16* bBase = Bs + (2 * w + ((l & 31) >> 4)) * 512 + (l & 15) * 8 + (l >> 5) * 256;
  auto WRITE_B = [&](int bi) {
    u16x8 v0, v1;
#pragma unroll
    for (int j = 0; j < 8; ++j) { v0[j] = f2bf(bq[j]); v1[j] = f2bf(bq[8 + j]); }
    *(u16x8*)(bBase + bi * 8192) = v0;
    *(u16x8*)(bBase + bi * 8192 + 128) = v1;
  };

  float bvf[4];
#pragma unroll
  for (int j = 0; j < 4; ++j) bvf[j] = bias[n0 + wn * 64 + j * 16 + fr];

  f32x4 acc[8][4] = {};
  const int NT = CDIM / 32;   // 32
  // prologue: A(0),A(1) gloads; B(0) regs -> drain -> LDS; B(1) regs in flight
  STAGE_A(0, 0); STAGE_A(1, 32);
  LOAD_B(0);
  WAITVM(0);
  WRITE_B(0);
  LOAD_B(1);
  WAITLGKM;
  __builtin_amdgcn_s_barrier();
  __builtin_amdgcn_sched_barrier(0);

#pragma unroll 1
  for (int t = 0; t < NT; ++t) {
    if (t + 2 < NT) STAGE_A((t + 2) % 3, (t + 2) * 32);
    const u16* ab = As + (t % 3) * 8192 + l * 8;
    const u16* bb = Bs + (t & 1) * 8192 + l * 8;
    bf16x8 av[4], bv[4], aw[4];
#pragma unroll
    for (int j = 0; j < 4; ++j) bv[j] = *(const bf16x8*)&bb[(wn * 4 + j) * 512];
#pragma unroll
    for (int i = 0; i < 4; ++i) av[i] = *(const bf16x8*)&ab[(wm * 8 + i) * 512];
#pragma unroll
    for (int i = 0; i < 4; ++i) aw[i] = *(const bf16x8*)&ab[(wm * 8 + 4 + i) * 512];
    __builtin_amdgcn_s_setprio(1);
#pragma unroll
    for (int i = 0; i < 4; ++i)
#pragma unroll
      for (int j = 0; j < 4; ++j)
        acc[i][j] = __builtin_amdgcn_mfma_f32_16x16x32_bf16(av[i], bv[j], acc[i][j], 0, 0, 0);
#pragma unroll
    for (int i = 0; i < 4; ++i)
#pragma unroll
      for (int j = 0; j < 4; ++j)
        acc[4 + i][j] = __builtin_amdgcn_mfma_f32_16x16x32_bf16(aw[i], bv[j], acc[4 + i][j], 0, 0, 0);
    __builtin_amdgcn_s_setprio(0);
    if (t + 1 < NT) {
      if (t + 2 < NT) { WAITVM(2); } else { WAITVM(0); }   // drain Bl(t+1); A(t+2) stays
      WRITE_B((t + 1) & 1);
      if (t + 2 < NT) LOAD_B(t + 2);
      WAITLGKM;                                            // ds_writes visible pre-barrier
      __builtin_amdgcn_s_barrier();
      __builtin_amdgcn_sched_barrier(0);
    }
  }

  // ---- epilogue: bias+relu+bf16, LDS-coalesced stores (two 128-row halves) ----
  for (int half = 0; half < 2; ++half) {
    __syncthreads();
    if (wm == half) {
#pragma unroll
      for (int i = 0; i < 8; ++i)
#pragma unroll
        for (int j = 0; j < 4; ++j) {
          const int col = wn * 64 + j * 16 + fr;
#pragma unroll
          for (int r = 0; r < 4; ++r) {
            float v = fmaxf(acc[i][j][r] + bvf[j], 0.0f);
            LDS[(i * 16 + fq * 4 + r) * 264 + col] = f2bf(v);
          }
        }
    }
    __syncthreads();
#pragma unroll
    for (int ps = 0; ps < 8; ++ps) {
      int idx = ps * 512 + tid, row = idx >> 5, c = idx & 31;
      u16x8 vv = *(const u16x8*)&LDS[row * 264 + c * 8];
      *(u16x8*)&Hu[(size_t)(m0 + half * 128 + row) * HDIM + n0 + c * 8] = vv;
    }
  }
}

// ---------------- GEMM2: Yu = Hu @ W2 + b2, W2 fp32 [H][C], fp32 out, 256x256 ----------------
__global__ __launch_bounds__(512, 2) void gemm_o_kernel(
    const u16* __restrict__ Hu, const float* __restrict__ W2, const float* __restrict__ RW2,
    const float* __restrict__ sh_b2, const float* __restrict__ rt_b2,
    const int* __restrict__ tile_expert,
    float* __restrict__ Yu) {
  // bijective XCD swizzle: nwg = 4*56 = 224, q = 28
  const int orig = blockIdx.y * 4 + blockIdx.x;
  const int wg = (orig & 7) * 28 + (orig >> 3);
  const int tile = wg >> 2, nidx = wg & 3;
  int e = tile_expert[tile];
  if (e < 0) return;
  const float* Bw = (e == 8) ? W2 : RW2 + (size_t)e * HDIM * CDIM;   // [H][C] fp32
  const float* bias = (e == 8) ? sh_b2 : rt_b2 + e * CDIM;

  __shared__ u16 LDS2[40960];  // 80KB
  u16* As = LDS2;
  u16* Bs = LDS2 + 24576;

  const int tid = threadIdx.x;
  const int l = tid & 63, w = tid >> 6;
  const int wm = w >> 2, wn = w & 3;        // 2M x 4N (wave tile 128x64)
  const int fr = l & 15, fq = l >> 4;
  const int m0 = tile * 256, n0 = nidx * 256;

  const u16* aSrc0 = Hu + (size_t)(m0 + 32 * w + fr) * HDIM + fq * 8;
  const u16* aSrc1 = Hu + (size_t)(m0 + 32 * w + 16 + fr) * HDIM + fq * 8;
  auto STAGE_A = [&](int bi, int kofs) {
    gload16(aSrc0 + kofs, As + bi * 8192 + (2 * w + 0) * 512);
    gload16(aSrc1 + kofs, As + bi * 8192 + (2 * w + 1) * 512);
  };

  const float* bSrc = Bw + (size_t)((l >> 5) * 16) * CDIM + (n0 + 32 * w + (l & 31));
  float bq[16];
  auto LOAD_B = [&](int kt) {
    const float* s = bSrc + (size_t)kt * 32 * CDIM;
#pragma unroll
    for (int j = 0; j < 16; ++j) bq[j] = s[(size_t)j * CDIM];
  };
  u16* bBase = Bs + (2 * w + ((l & 31) >> 4)) * 512 + (l & 15) * 8 + (l >> 5) * 256;
  auto WRITE_B = [&](int bi) {
    u16x8 v0, v1;
#pragma unroll
    for (int j = 0; j < 8; ++j) { v0[j] = f2bf(bq[j]); v1[j] = f2bf(bq[8 + j]); }
    *(u16x8*)(bBase + bi * 8192) = v0;
    *(u16x8*)(bBase + bi * 8192 + 128) = v1;
  };

  float bvf[4];
#pragma unroll
  for (int j = 0; j < 4; ++j) bvf[j] = bias[n0 + wn * 64 + j * 16 + fr];

  f32x4 acc[8][4] = {};
  const int NT = HDIM / 32;   // 128
  STAGE_A(0, 0); STAGE_A(1, 32);
  LOAD_B(0);
  WAITVM(0);
  WRITE_B(0);
  LOAD_B(1);
  WAITLGKM;
  __builtin_amdgcn_s_barrier();
  __builtin_amdgcn_sched_barrier(0);

#pragma unroll 1
  for (int t = 0; t < NT; ++t) {
    if (t + 2 < NT) STAGE_A((t + 2) % 3, (t + 2) * 32);
    const u16* ab = As + (t % 3) * 8192 + l * 8;
    const u16* bb = Bs + (t & 1) * 8192 + l * 8;
    bf16x8 av[4], bv[4], aw[4];
#pragma unroll
    for (int j = 0; j < 4; ++j) bv[j] = *(const bf16x8*)&bb[(wn * 4 + j) * 512];
#pragma unroll
    for (int i = 0; i < 4; ++i) av[i] = *(const bf16x8*)&ab[(wm * 8 + i) * 512];
#pragma unroll
    for (int i = 0; i < 4; ++i) aw[i] = *(const bf16x8*)&ab[(wm * 8 + 4 + i) * 512];
    __builtin_amdgcn_s_setprio(1);
#pragma unroll
    for (int i = 0; i < 4; ++i)
#pragma unroll
      for (int j = 0; j < 4; ++j)
        acc[i][j] = __builtin_amdgcn_mfma_f32_16x16x32_bf16(av[i], bv[j], acc[i][j], 0, 0, 0);
#pragma unroll
    for (int i = 0; i < 4; ++i)
#pragma unroll
      for (int j = 0; j < 4; ++j)
        acc[4 + i][j] = __builtin_amdgcn_mfma_f32_16x16x32_bf16(aw[i], bv[j], acc[4 + i][j], 0, 0, 0);
    __builtin_amdgcn_s_setprio(0);
    if (t + 1 < NT) {
      if (t + 2 < NT) { WAITVM(2); } else { WAITVM(0); }
      WRITE_B((t + 1) & 1);
      if (t + 2 < NT) LOAD_B(t + 2);
      WAITLGKM;
      __builtin_amdgcn_s_barrier();
      __builtin_amdgcn_sched_barrier(0);
    }
  }

  const size_t mb = m0 + wm * 128;
#pragma unroll
  for (int j = 0; j < 4; ++j) {
    const int n_g = n0 + wn * 64 + j * 16 + fr;
#pragma unroll
    for (int i = 0; i < 8; ++i)
#pragma unroll
      for (int r = 0; r < 4; ++r)
        Yu[(mb + i * 16 + fq * 4 + r) * (size_t)CDIM + n_g] = acc[i][j][r] + bvf[j];
  }
}

// ---------------- combine: out = shared + w0*expert0 + w1*expert1 ----------------
__global__ void combine_kernel(const float* __restrict__ Yu, const float* __restrict__ w01,
                               const int* __restrict__ slot_of, float* __restrict__ out) {
  int gid = blockIdx.x * 256 + threadIdx.x;   // 4096 blocks; 256 float4 per token row
  int t = gid >> 8;
  int c4 = gid & 255;
  int s0 = slot_of[t * 2], s1 = slot_of[t * 2 + 1];
  float wq0 = w01[t * 2], wq1 = w01[t * 2 + 1];
  float4 a  = ((const float4*)(Yu + (size_t)t  * CDIM))[c4];
  float4 b0 = ((const float4*)(Yu + (size_t)s0 * CDIM))[c4];
  float4 b1 = ((const float4*)(Yu + (size_t)s1 * CDIM))[c4];
  float4 rv;
  rv.x = a.x + wq0 * b0.x + wq1 * b1.x;
  rv.y = a.y + wq0 * b0.y + wq1 * b1.y;
  rv.z = a.z + wq0 * b0.z + wq1 * b1.z;
  rv.w = a.w + wq0 * b0.w + wq1 * b1.w;
  ((float4*)out)[gid] = rv;
}

extern "C" void kernel_launch(void* const* d_in, const int* in_sizes, int n_in,
                              void* d_out, int out_size, void* d_ws, size_t ws_size,
                              hipStream_t stream) {
  const float* X        = (const float*)d_in[0];   // [4096,1024]
  const float* router_w = (const float*)d_in[1];   // [1024,8]
  const float* sh_w1    = (const float*)d_in[2];   // [1024,4096]  [C][H]
  const float* sh_b1    = (const float*)d_in[3];   // [4096]
  const float* sh_w2    = (const float*)d_in[4];   // [4096,1024]  [H][C]
  const float* sh_b2    = (const float*)d_in[5];   // [1024]
  const float* rt_w1    = (const float*)d_in[6];   // [8,1024,4096]
  const float* rt_b1    = (const float*)d_in[7];   // [8,4096]
  const float* rt_w2    = (const float*)d_in[8];   // [8,4096,1024]
  const float* rt_b2    = (const float*)d_in[9];   // [8,1024]
  float* out = (float*)d_out;

  // ---- workspace layout ----
  char* p = (char*)d_ws;
  auto take = [&](size_t bytes) { char* q = p; p += (bytes + 255) & ~(size_t)255; return q; };
  u16*  Xb   = (u16*)take((size_t)NTOK * CDIM * 2);        //   8 MB
  u16*  Hu   = (u16*)take((size_t)SLOTS * HDIM * 2);       // 112 MB
  float* Yu  = (float*)take((size_t)SLOTS * CDIM * 4);     //  56 MB
  float* w01 = (float*)take((size_t)NTOK * 2 * 4);
  int*  e01  = (int*)take((size_t)NTOK * 2 * 4);
  int*  slot_of = (int*)take((size_t)NTOK * 2 * 4);
  int*  order   = (int*)take((size_t)SLOTS * 4);
  int*  tile_expert = (int*)take((size_t)NTILES * 4);
  float* pP  = (float*)take((size_t)RBLK * 8 * 4);         //  32 KB router prob partials
  int*  pC   = (int*)take((size_t)RBLK * 8 * 4);           //  32 KB router count partials
  int*  cursor = (int*)take(256);
  int*  roff   = (int*)take(256);
  size_t need = (size_t)(p - (char*)d_ws);
  if (ws_size < need) return;  // insufficient scratch -> fail visibly (poisoned out)

  // ---- pipeline ----
  init_kernel<<<NTILES, 256, 0, stream>>>(order, tile_expert, cursor);
  router_kernel<<<RBLK, 256, 0, stream>>>(X, router_w, Xb, w01, e01, pP, pC);
  setup_kernel<<<1, 256, 0, stream>>>(pP, pC, roff, tile_expert, out + (size_t)NTOK * CDIM);
  scatter_kernel<<<NTOK / 256, 256, 0, stream>>>(e01, roff, cursor, order, slot_of);
  gemm_h_kernel<<<dim3(16, NTILES), 512, 0, stream>>>(
      Xb, sh_w1, rt_w1, sh_b1, rt_b1, tile_expert, order, Hu);
  gemm_o_kernel<<<dim3(4, NTILES), 512, 0, stream>>>(
      Hu, sh_w2, rt_w2, sh_b2, rt_b2, tile_expert, Yu);
  combine_kernel<<<(NTOK * CDIM / 4) / 256, 256, 0, stream>>>(Yu, w01, slot_of, out);
}

// Round 17
// 377.021 us; speedup vs baseline: 1.1332x; 1.0440x over previous
//
#include <hip/hip_runtime.h>

// MoE layer: B=4,T=1024,C=1024,H=4096,E=8, top-2 routing, shared expert.
// Sparse formulation: only top-2 experts per token are computed.
//
// R17 = R16 (393.6us) + gemm_o moved to BK=64 super-tiles: halves the
// barrier+drain tail count (128 -> 64) on the kernel with the thinnest
// latency hiding (224 blocks = 1 block/CU = 2 waves/SIMD, tails exposed).
// A: 3 x 32KB buffers (two 32-k sub-images, 4 gload16/super-tile);
// B: 2 x 32KB, bq0/bq1 named reg buffers; tail WAITVM(4) drains exactly
// B(t+1) (issued one full 64-MFMA super-tile earlier), A(t+2) stays in
// flight. LDS 160KB -- free for gemm_o (1 block/CU regardless of LDS).
// gemm_h unchanged (2 blocks/CU at 80KB is its win). f2bf stays native
// cast (R16: -24us from paired v_cvt_pk_bf16_f32).

typedef unsigned short u16;
typedef __bf16 bf16x8 __attribute__((ext_vector_type(8)));
typedef float f32x4 __attribute__((ext_vector_type(4)));
typedef u16 u16x8 __attribute__((ext_vector_type(8)));

#define NTOK 4096
#define CDIM 1024
#define HDIM 4096
#define NEXP 8
#define SLOTS 14336   // 4096 shared (16 tiles) + 10240 routed capacity (256-aligned segs)
#define NTILES 56     // SLOTS/256
#define RBLK 1024     // router grid (4 tokens/block)

#define WAITVM(N) do { asm volatile("s_waitcnt vmcnt(" #N ")" ::: "memory"); } while (0)
#define WAITLGKM do { asm volatile("s_waitcnt lgkmcnt(0)" ::: "memory"); } while (0)

static __device__ __forceinline__ u16 f2bf(float f) {   // native cast -> v_cvt_pk_bf16_f32 (RNE)
  union { __bf16 h; u16 u; } cv;
  cv.h = (__bf16)f;
  return cv.u;
}

static __device__ __forceinline__ void gload16(const void* g, void* l) {
  __builtin_amdgcn_global_load_lds((const __attribute__((address_space(1))) unsigned int*)g,
                                   (__attribute__((address_space(3))) unsigned int*)l,
                                   16, 0, 0);
}

// ---------------- init: zero cursor, identity/pad slot map ----------------
__global__ void init_kernel(int* order, int* tile_expert, int* cursor) {
  int i = blockIdx.x * 256 + threadIdx.x;      // grid 56*256 = 14336
  if (i < SLOTS) order[i] = (i < NTOK) ? i : -1;
  if (i < NTILES) tile_expert[i] = (i < 16) ? 8 : -1;   // tiles 0..15 = shared expert
  if (i < NEXP) cursor[i] = 0;
}

// ---------------- router + X->bf16 fused: 1 wave/token, NO global atomics ----------------
__global__ __launch_bounds__(256) void router_kernel(
    const float* __restrict__ X, const float* __restrict__ rw,
    u16* __restrict__ Xb,
    float* __restrict__ w01, int* __restrict__ e01,
    float* __restrict__ pP, int* __restrict__ pC) {
  __shared__ float wP[4][8];
  __shared__ int wE[4][2];
  const int tid = threadIdx.x;
  const int w = tid >> 6, l = tid & 63;
  const int wid = blockIdx.x * 4 + w;   // token
  const float* x = X + (size_t)wid * CDIM;
  u16* xbrow = Xb + (size_t)wid * CDIM;
  float s[8] = {0.f,0.f,0.f,0.f,0.f,0.f,0.f,0.f};
#pragma unroll 4
  for (int i = 0; i < 16; ++i) {
    int c = i * 64 + l;
    float xv = x[c];
    xbrow[c] = f2bf(xv);                // fused bf16 conversion
    const float4* rp = (const float4*)(rw + c * 8);
    float4 r0 = rp[0], r1 = rp[1];
    s[0] += xv * r0.x; s[1] += xv * r0.y; s[2] += xv * r0.z; s[3] += xv * r0.w;
    s[4] += xv * r1.x; s[5] += xv * r1.y; s[6] += xv * r1.z; s[7] += xv * r1.w;
  }
#pragma unroll
  for (int off = 32; off; off >>= 1)
#pragma unroll
    for (int e = 0; e < 8; ++e) s[e] += __shfl_down(s[e], off);
  if (l == 0) {
    float m = s[0];
#pragma unroll
    for (int e = 1; e < 8; ++e) m = fmaxf(m, s[e]);
    float p[8], d = 0.f;
#pragma unroll
    for (int e = 0; e < 8; ++e) { p[e] = expf(s[e] - m); d += p[e]; }
    float inv = 1.f / d;
#pragma unroll
    for (int e = 0; e < 8; ++e) p[e] *= inv;
    int e0 = 0;
#pragma unroll
    for (int e = 1; e < 8; ++e) if (p[e] > p[e0]) e0 = e;   // ties -> lowest idx (jax)
    int e1 = -1;
#pragma unroll
    for (int e = 0; e < 8; ++e) if (e != e0 && (e1 < 0 || p[e] > p[e1])) e1 = e;
    w01[wid * 2] = p[e0]; w01[wid * 2 + 1] = p[e1];
    e01[wid * 2] = e0;    e01[wid * 2 + 1] = e1;
#pragma unroll
    for (int e = 0; e < 8; ++e) wP[w][e] = p[e];
    wE[w][0] = e0; wE[w][1] = e1;
  }
  __syncthreads();
  if (tid < 8) {
    pP[blockIdx.x * 8 + tid] = wP[0][tid] + wP[1][tid] + wP[2][tid] + wP[3][tid];
    int c = 0;
#pragma unroll
    for (int v = 0; v < 4; ++v) c += (wE[v][0] == tid) + (wE[v][1] == tid);
    pC[blockIdx.x * 8 + tid] = c;
  }
}

// ---------------- setup: reduce partials, offsets (256-aligned), tile map, aux ----------------
__global__ __launch_bounds__(256) void setup_kernel(
    const float* __restrict__ pP, const int* __restrict__ pC,
    int* __restrict__ roff, int* __restrict__ tile_expert, float* __restrict__ out_aux) {
  __shared__ float sP[32][8];
  __shared__ int   sC[32][8];
  const int tid = threadIdx.x;
  const int e = tid & 7, g = tid >> 3;   // 32 groups x 8 experts
  float fs = 0.f; int cs = 0;
  for (int b = g; b < RBLK; b += 32) { fs += pP[b * 8 + e]; cs += pC[b * 8 + e]; }
  sP[g][e] = fs; sC[g][e] = cs;
  __syncthreads();
  if (tid == 0) {
    float P[8]; int C[8];
    for (int e2 = 0; e2 < 8; ++e2) {
      float f2 = 0.f; int c2 = 0;
      for (int g2 = 0; g2 < 32; ++g2) { f2 += sP[g2][e2]; c2 += sC[g2][e2]; }
      P[e2] = f2; C[e2] = c2;
    }
    int off = NTOK;
    float a = 0.f;
    for (int e2 = 0; e2 < NEXP; ++e2) {
      roff[e2] = off;
      int nt = (C[e2] + 255) >> 8;
      int t0 = off >> 8;
      for (int i = 0; i < nt; ++i) tile_expert[t0 + i] = e2;
      off += nt << 8;
      a += (C[e2] * (1.f / NTOK)) * (P[e2] * (1.f / NTOK));
    }
    out_aux[0] = (float)NEXP * a;
  }
}

// ---------------- scatter: token -> slots, block-aggregated cursor ----------------
__global__ __launch_bounds__(256) void scatter_kernel(
    const int* __restrict__ e01, const int* __restrict__ roff,
    int* __restrict__ cursor, int* __restrict__ order, int* __restrict__ slot_of) {
  __shared__ int cnt_l[8];
  __shared__ int base_l[8];
  const int tid = threadIdx.x;
  const int t = blockIdx.x * 256 + tid;   // grid 16 blocks
  if (tid < 8) cnt_l[tid] = 0;
  __syncthreads();
  int e0 = e01[t * 2], e1 = e01[t * 2 + 1];
  int p0 = atomicAdd(&cnt_l[e0], 1);      // LDS atomics
  int p1 = atomicAdd(&cnt_l[e1], 1);
  __syncthreads();
  if (tid < 8) base_l[tid] = atomicAdd(&cursor[tid], cnt_l[tid]);  // 8 global atomics/block
  __syncthreads();
  int s0 = roff[e0] + base_l[e0] + p0;
  int s1 = roff[e1] + base_l[e1] + p1;
  order[s0] = t; order[s1] = t;
  slot_of[t * 2] = s0; slot_of[t * 2 + 1] = s1;
}

// LDS layout: per 256x32 operand sub-image, 16 chunks of 1KB; chunk g =
// rows 16g..16g+15, slot l = (row 16g+(l&15), k (l>>4)*8..+7). All LDS ops
// wave-uniform-base + disjoint 16B slots -> zero bank conflicts (R3-R16).
// gemm_h: BK=32 (A 3x16KB gload16 dist-2; B 2x16KB reg-staged). gemm_o:
// BK=64 super-tiles (two sub-images back-to-back; A 3x32KB, B 2x32KB).

// ---------------- GEMM1: hidden = relu(A @ W1 + b1), W1 fp32 [C][H], out bf16 ----------------
__global__ __launch_bounds__(512, 2) void gemm_h_kernel(
    const u16* __restrict__ Xb, const float* __restrict__ W1, const float* __restrict__ RW1,
    const float* __restrict__ sh_b1, const float* __restrict__ rt_b1,
    const int* __restrict__ tile_expert, const int* __restrict__ order,
    u16* __restrict__ Hu) {
  // bijective XCD swizzle, TILE-FAST decode: nwg = 896 = 8 XCD x 112;
  // consecutive wg -> consecutive tiles at same nidx (B-panel L2 reuse).
  const int orig = blockIdx.y * 16 + blockIdx.x;
  const int wg = (orig & 7) * 112 + (orig >> 3);
  const int tile = wg % 56, nidx = wg / 56;
  int e = tile_expert[tile];
  if (e < 0) return;
  const float* Bw = (e == 8) ? W1 : RW1 + (size_t)e * CDIM * HDIM;   // [C][H] fp32
  const float* bias = (e == 8) ? sh_b1 : rt_b1 + e * HDIM;

  __shared__ u16 LDS[40960];   // 80KB: A 3x8192 + B 2x8192; epilogue [128][264]
  u16* As = LDS;
  u16* Bs = LDS + 24576;

  const int tid = threadIdx.x;
  const int l = tid & 63, w = tid >> 6;     // 8 waves
  const int wm = w >> 2, wn = w & 3;        // 2M x 4N (wave tile 128x64)
  const int fr = l & 15, fq = l >> 4;
  const int m0 = tile * 256, n0 = nidx * 256;

  int tok0 = order[m0 + 32 * w + fr];      if (tok0 < 0) tok0 = 0;
  int tok1 = order[m0 + 32 * w + 16 + fr]; if (tok1 < 0) tok1 = 0;
  const u16* aSrc0 = Xb + (size_t)tok0 * CDIM + fq * 8;
  const u16* aSrc1 = Xb + (size_t)tok1 * CDIM + fq * 8;
  auto STAGE_A = [&](int bi, int kofs) {
    gload16(aSrc0 + kofs, As + bi * 8192 + (2 * w + 0) * 512);
    gload16(aSrc1 + kofs, As + bi * 8192 + (2 * w + 1) * 512);
  };

  // B: fp32 [CDIM][HDIM]; lane covers n = n0+32w+(l&31), k base (l>>5)*16
  const float* bSrc = Bw + (size_t)((l >> 5) * 16) * HDIM + (n0 + 32 * w + (l & 31));
  float bq[16];
  auto LOAD_B = [&](int kt) {
    const float* s = bSrc + (size_t)kt * 32 * HDIM;
#pragma unroll
    for (int j = 0; j < 16; ++j) bq[j] = s[(size_t)j * HDIM];
  };
  u16* bBase = Bs + (2 * w + ((l & 31) >> 4)) * 512 + (l & 15) * 8 + (l >> 5) * 256;
  auto WRITE_B = [&](int bi) {
    u16x8 v0, v1;
#pragma unroll
    for (int j = 0; j < 8; ++j) { v0[j] = f2bf(bq[j]); v1[j] = f2bf(bq[8 + j]); }
    *(u16x8*)(bBase + bi * 8192) = v0;
    *(u16x8*)(bBase + bi * 8192 + 128) = v1;
  };

  float bvf[4];
#pragma unroll
  for (int j = 0; j < 4; ++j) bvf[j] = bias[n0 + wn * 64 + j * 16 + fr];

  f32x4 acc[8][4] = {};
  const int NT = CDIM / 32;   // 32
  // prologue: A(0),A(1) gloads; B(0) regs -> drain -> LDS; B(1) regs in flight
  STAGE_A(0, 0); STAGE_A(1, 32);
  LOAD_B(0);
  WAITVM(0);
  WRITE_B(0);
  LOAD_B(1);
  WAITLGKM;
  __builtin_amdgcn_s_barrier();
  __builtin_amdgcn_sched_barrier(0);

#pragma unroll 1
  for (int t = 0; t < NT; ++t) {
    if (t + 2 < NT) STAGE_A((t + 2) % 3, (t + 2) * 32);
    const u16* ab = As + (t % 3) * 8192 + l * 8;
    const u16* bb = Bs + (t & 1) * 8192 + l * 8;
    bf16x8 av[4], bv[4], aw[4];
#pragma unroll
    for (int j = 0; j < 4; ++j) bv[j] = *(const bf16x8*)&bb[(wn * 4 + j) * 512];
#pragma unroll
    for (int i = 0; i < 4; ++i) av[i] = *(const bf16x8*)&ab[(wm * 8 + i) * 512];
#pragma unroll
    for (int i = 0; i < 4; ++i) aw[i] = *(const bf16x8*)&ab[(wm * 8 + 4 + i) * 512];
    __builtin_amdgcn_s_setprio(1);
#pragma unroll
    for (int i = 0; i < 4; ++i)
#pragma unroll
      for (int j = 0; j < 4; ++j)
        acc[i][j] = __builtin_amdgcn_mfma_f32_16x16x32_bf16(av[i], bv[j], acc[i][j], 0, 0, 0);
#pragma unroll
    for (int i = 0; i < 4; ++i)
#pragma unroll
      for (int j = 0; j < 4; ++j)
        acc[4 + i][j] = __builtin_amdgcn_mfma_f32_16x16x32_bf16(aw[i], bv[j], acc[4 + i][j], 0, 0, 0);
    __builtin_amdgcn_s_setprio(0);
    if (t + 1 < NT) {
      if (t + 2 < NT) { WAITVM(2); } else { WAITVM(0); }   // drain Bl(t+1); A(t+2) stays
      WRITE_B((t + 1) & 1);
      if (t + 2 < NT) LOAD_B(t + 2);
      WAITLGKM;                                            // ds_writes visible pre-barrier
      __builtin_amdgcn_s_barrier();
      __builtin_amdgcn_sched_barrier(0);
    }
  }

  // ---- epilogue: bias+relu+bf16, LDS-coalesced stores (two 128-row halves) ----
  for (int half = 0; half < 2; ++half) {
    __syncthreads();
    if (wm == half) {
#pragma unroll
      for (int i = 0; i < 8; ++i)
#pragma unroll
        for (int j = 0; j < 4; ++j) {
          const int col = wn * 64 + j * 16 + fr;
#pragma unroll
          for (int r = 0; r < 4; ++r) {
            float v = fmaxf(acc[i][j][r] + bvf[j], 0.0f);
            LDS[(i * 16 + fq * 4 + r) * 264 + col] = f2bf(v);
          }
        }
    }
    __syncthreads();
#pragma unroll
    for (int ps = 0; ps < 8; ++ps) {
      int idx = ps * 512 + tid, row = idx >> 5, c = idx & 31;
      u16x8 vv = *(const u16x8*)&LDS[row * 264 + c * 8];
      *(u16x8*)&Hu[(size_t)(m0 + half * 128 + row) * HDIM + n0 + c * 8] = vv;
    }
  }
}

// ---------------- GEMM2: Yu = Hu @ W2 + b2, W2 fp32 [H][C], fp32 out ----------------
// 256x256 tile, BK=64 super-tiles (halved tail count), 160KB LDS (1 blk/CU
// anyway: 224 blocks on 256 CUs).
__global__ __launch_bounds__(512, 2) void gemm_o_kernel(
    const u16* __restrict__ Hu, const float* __restrict__ W2, const float* __restrict__ RW2,
    const float* __restrict__ sh_b2, const float* __restrict__ rt_b2,
    const int* __restrict__ tile_expert,
    float* __restrict__ Yu) {
  // bijective XCD swizzle: nwg = 4*56 = 224, q = 28
  const int orig = blockIdx.y * 4 + blockIdx.x;
  const int wg = (orig & 7) * 28 + (orig >> 3);
  const int tile = wg >> 2, nidx = wg & 3;
  int e = tile_expert[tile];
  if (e < 0) return;
  const float* Bw = (e == 8) ? W2 : RW2 + (size_t)e * HDIM * CDIM;   // [H][C] fp32
  const float* bias = (e == 8) ? sh_b2 : rt_b2 + e * CDIM;

  __shared__ u16 LDS2[81920];  // 160KB: A 3x16384 u16 + B 2x16384 u16
  u16* As = LDS2;
  u16* Bs = LDS2 + 49152;

  const int tid = threadIdx.x;
  const int l = tid & 63, w = tid >> 6;
  const int wm = w >> 2, wn = w & 3;        // 2M x 4N (wave tile 128x64)
  const int fr = l & 15, fq = l >> 4;
  const int m0 = tile * 256, n0 = nidx * 256;

  const u16* aSrc0 = Hu + (size_t)(m0 + 32 * w + fr) * HDIM + fq * 8;
  const u16* aSrc1 = Hu + (size_t)(m0 + 32 * w + 16 + fr) * HDIM + fq * 8;
  auto STAGE_A = [&](int bi, int kofs) {   // super-tile: two 32-k sub-images
    u16* base = As + bi * 16384;
    gload16(aSrc0 + kofs,      base + (2 * w + 0) * 512);
    gload16(aSrc1 + kofs,      base + (2 * w + 1) * 512);
    gload16(aSrc0 + kofs + 32, base + 8192 + (2 * w + 0) * 512);
    gload16(aSrc1 + kofs + 32, base + 8192 + (2 * w + 1) * 512);
  };

  const float* bSrc = Bw + (size_t)((l >> 5) * 16) * CDIM + (n0 + 32 * w + (l & 31));
  float bq0[16], bq1[16];   // named (static) reg buffers for the two k-halves
  auto LOAD_B = [&](int T) {   // 32 loads: k = T*64 + {0,32} + (l>>5)*16 + j
    const float* s0 = bSrc + (size_t)T * 64 * CDIM;
    const float* s1 = s0 + (size_t)32 * CDIM;
#pragma unroll
    for (int j = 0; j < 16; ++j) bq0[j] = s0[(size_t)j * CDIM];
#pragma unroll
    for (int j = 0; j < 16; ++j) bq1[j] = s1[(size_t)j * CDIM];
  };
  u16* bBase = Bs + (2 * w + ((l & 31) >> 4)) * 512 + (l & 15) * 8 + (l >> 5) * 256;
  auto WRITE_B = [&](int bi) {
    u16x8 v0, v1, v2, v3;
#pragma unroll
    for (int j = 0; j < 8; ++j) {
      v0[j] = f2bf(bq0[j]); v1[j] = f2bf(bq0[8 + j]);
      v2[j] = f2bf(bq1[j]); v3[j] = f2bf(bq1[8 + j]);
    }
    *(u16x8*)(bBase + bi * 16384) = v0;
    *(u16x8*)(bBase + bi * 16384 + 128) = v1;
    *(u16x8*)(bBase + bi * 16384 + 8192) = v2;
    *(u16x8*)(bBase + bi * 16384 + 8192 + 128) = v3;
  };

  float bvf[4];
#pragma unroll
  for (int j = 0; j < 4; ++j) bvf[j] = bias[n0 + wn * 64 + j * 16 + fr];

  f32x4 acc[8][4] = {};
  const int NT = HDIM / 64;   // 64 super-tiles
  STAGE_A(0, 0); STAGE_A(1, 64);
  LOAD_B(0);
  WAITVM(0);
  WRITE_B(0);
  LOAD_B(1);
  WAITLGKM;
  __builtin_amdgcn_s_barrier();
  __builtin_amdgcn_sched_barrier(0);

#pragma unroll 1
  for (int t = 0; t < NT; ++t) {
    if (t + 2 < NT) STAGE_A((t + 2) % 3, (t + 2) * 64);
    const u16* ab = As + (t % 3) * 16384 + l * 8;
    const u16* bb = Bs + (t & 1) * 16384 + l * 8;
    // ---- sub-image 0 (k 0..31) ----
    {
      bf16x8 av[4], bv[4], aw[4];
#pragma unroll
      for (int j = 0; j < 4; ++j) bv[j] = *(const bf16x8*)&bb[(wn * 4 + j) * 512];
#pragma unroll
      for (int i = 0; i < 4; ++i) av[i] = *(const bf16x8*)&ab[(wm * 8 + i) * 512];
#pragma unroll
      for (int i = 0; i < 4; ++i) aw[i] = *(const bf16x8*)&ab[(wm * 8 + 4 + i) * 512];
      __builtin_amdgcn_s_setprio(1);
#pragma unroll
      for (int i = 0; i < 4; ++i)
#pragma unroll
        for (int j = 0; j < 4; ++j)
          acc[i][j] = __builtin_amdgcn_mfma_f32_16x16x32_bf16(av[i], bv[j], acc[i][j], 0, 0, 0);
#pragma unroll
      for (int i = 0; i < 4; ++i)
#pragma unroll
        for (int j = 0; j < 4; ++j)
          acc[4 + i][j] = __builtin_amdgcn_mfma_f32_16x16x32_bf16(aw[i], bv[j], acc[4 + i][j], 0, 0, 0);
      __builtin_amdgcn_s_setprio(0);
    }
    // ---- sub-image 1 (k 32..63) ----
    {
      const u16* ab1 = ab + 8192;
      const u16* bb1 = bb + 8192;
      bf16x8 av[4], bv[4], aw[4];
#pragma unroll
      for (int j = 0; j < 4; ++j) bv[j] = *(const bf16x8*)&bb1[(wn * 4 + j) * 512];
#pragma unroll
      for (int i = 0; i < 4; ++i) av[i] = *(const bf16x8*)&ab1[(wm * 8 + i) * 512];
#pragma unroll
      for (int i = 0; i < 4; ++i) aw[i] = *(const bf16x8*)&ab1[(wm * 8 + 4 + i) * 512];
      __builtin_amdgcn_s_setprio(1);
#pragma unroll
      for (int i = 0; i < 4; ++i)
#pragma unroll
        for (int j = 0; j < 4; ++j)
          acc[i][j] = __builtin_amdgcn_mfma_f32_16x16x32_bf16(av[i], bv[j], acc[i][j], 0, 0, 0);
#pragma unroll
      for (int i = 0; i < 4; ++i)
#pragma unroll
        for (int j = 0; j < 4; ++j)
          acc[4 + i][j] = __builtin_amdgcn_mfma_f32_16x16x32_bf16(aw[i], bv[j], acc[4 + i][j], 0, 0, 0);
      __builtin_amdgcn_s_setprio(0);
    }
    if (t + 1 < NT) {
      if (t + 2 < NT) { WAITVM(4); } else { WAITVM(0); }   // drain B(t+1) 32; A(t+2) 4 stay
      WRITE_B((t + 1) & 1);
      if (t + 2 < NT) LOAD_B(t + 2);
      WAITLGKM;
      __builtin_amdgcn_s_barrier();
      __builtin_amdgcn_sched_barrier(0);
    }
  }

  const size_t mb = m0 + wm * 128;
#pragma unroll
  for (int j = 0; j < 4; ++j) {
    const int n_g = n0 + wn * 64 + j * 16 + fr;
#pragma unroll
    for (int i = 0; i < 8; ++i)
#pragma unroll
      for (int r = 0; r < 4; ++r)
        Yu[(mb + i * 16 + fq * 4 + r) * (size_t)CDIM + n_g] = acc[i][j][r] + bvf[j];
  }
}

// ---------------- combine: out = shared + w0*expert0 + w1*expert1 ----------------
__global__ void combine_kernel(const float* __restrict__ Yu, const float* __restrict__ w01,
                               const int* __restrict__ slot_of, float* __restrict__ out) {
  int gid = blockIdx.x * 256 + threadIdx.x;   // 4096 blocks; 256 float4 per token row
  int t = gid >> 8;
  int c4 = gid & 255;
  int s0 = slot_of[t * 2], s1 = slot_of[t * 2 + 1];
  float wq0 = w01[t * 2], wq1 = w01[t * 2 + 1];
  float4 a  = ((const float4*)(Yu + (size_t)t  * CDIM))[c4];
  float4 b0 = ((const float4*)(Yu + (size_t)s0 * CDIM))[c4];
  float4 b1 = ((const float4*)(Yu + (size_t)s1 * CDIM))[c4];
  float4 rv;
  rv.x = a.x + wq0 * b0.x + wq1 * b1.x;
  rv.y = a.y + wq0 * b0.y + wq1 * b1.y;
  rv.z = a.z + wq0 * b0.z + wq1 * b1.z;
  rv.w = a.w + wq0 * b0.w + wq1 * b1.w;
  ((float4*)out)[gid] = rv;
}

extern "C" void kernel_launch(void* const* d_in, const int* in_sizes, int n_in,
                              void* d_out, int out_size, void* d_ws, size_t ws_size,
                              hipStream_t stream) {
  const float* X        = (const float*)d_in[0];   // [4096,1024]
  const float* router_w = (const float*)d_in[1];   // [1024,8]
  const float* sh_w1    = (const float*)d_in[2];   // [1024,4096]  [C][H]
  const float* sh_b1    = (const float*)d_in[3];   // [4096]
  const float* sh_w2    = (const float*)d_in[4];   // [4096,1024]  [H][C]
  const float* sh_b2    = (const float*)d_in[5];   // [1024]
  const float* rt_w1    = (const float*)d_in[6];   // [8,1024,4096]
  const float* rt_b1    = (const float*)d_in[7];   // [8,4096]
  const float* rt_w2    = (const float*)d_in[8];   // [8,4096,1024]
  const float* rt_b2    = (const float*)d_in[9];   // [8,1024]
  float* out = (float*)d_out;

  // ---- workspace layout ----
  char* p = (char*)d_ws;
  auto take = [&](size_t bytes) { char* q = p; p += (bytes + 255) & ~(size_t)255; return q; };
  u16*  Xb   = (u16*)take((size_t)NTOK * CDIM * 2);        //   8 MB
  u16*  Hu   = (u16*)take((size_t)SLOTS * HDIM * 2);       // 112 MB
  float* Yu  = (float*)take((size_t)SLOTS * CDIM * 4);     //  56 MB
  float* w01 = (float*)take((size_t)NTOK * 2 * 4);
  int*  e01  = (int*)take((size_t)NTOK * 2 * 4);
  int*  slot_of = (int*)take((size_t)NTOK * 2 * 4);
  int*  order   = (int*)take((size_t)SLOTS * 4);
  int*  tile_expert = (int*)take((size_t)NTILES * 4);
  float* pP  = (float*)take((size_t)RBLK * 8 * 4);         //  32 KB router prob partials
  int*  pC   = (int*)take((size_t)RBLK * 8 * 4);           //  32 KB router count partials
  int*  cursor = (int*)take(256);
  int*  roff   = (int*)take(256);
  size_t need = (size_t)(p - (char*)d_ws);
  if (ws_size < need) return;  // insufficient scratch -> fail visibly (poisoned out)

  // ---- pipeline ----
  init_kernel<<<NTILES, 256, 0, stream>>>(order, tile_expert, cursor);
  router_kernel<<<RBLK, 256, 0, stream>>>(X, router_w, Xb, w01, e01, pP, pC);
  setup_kernel<<<1, 256, 0, stream>>>(pP, pC, roff, tile_expert, out + (size_t)NTOK * CDIM);
  scatter_kernel<<<NTOK / 256, 256, 0, stream>>>(e01, roff, cursor, order, slot_of);
  gemm_h_kernel<<<dim3(16, NTILES), 512, 0, stream>>>(
      Xb, sh_w1, rt_w1, sh_b1, rt_b1, tile_expert, order, Hu);
  gemm_o_kernel<<<dim3(4, NTILES), 512, 0, stream>>>(
      Hu, sh_w2, rt_w2, sh_b2, rt_b2, tile_expert, Yu);
  combine_kernel<<<(NTOK * CDIM / 4) / 256, 256, 0, stream>>>(Yu, w01, slot_of, out);
}

// Round 18
// 373.250 us; speedup vs baseline: 1.1447x; 1.0101x over previous
//
#include <hip/hip_runtime.h>

// MoE layer: B=4,T=1024,C=1024,H=4096,E=8, top-2 routing, shared expert.
// Sparse formulation: only top-2 experts per token are computed.
//
// R18 = R17 (377us) + gemm_h also moved to BK=64 super-tiles (the template
// R17 validated on gemm_o at 905 TF): tails 32 -> 16, A 3x32KB + B 2x32KB
// = 160KB LDS (1 blk/CU; dispatch-tail arithmetic neutral: 896/(512*2) ==
// 896/(256*4) = 87.5%). gemm_o, router, combine byte-identical to R17.

typedef unsigned short u16;
typedef __bf16 bf16x8 __attribute__((ext_vector_type(8)));
typedef float f32x4 __attribute__((ext_vector_type(4)));
typedef u16 u16x8 __attribute__((ext_vector_type(8)));

#define NTOK 4096
#define CDIM 1024
#define HDIM 4096
#define NEXP 8
#define SLOTS 14336   // 4096 shared (16 tiles) + 10240 routed capacity (256-aligned segs)
#define NTILES 56     // SLOTS/256
#define RBLK 1024     // router grid (4 tokens/block)

#define WAITVM(N) do { asm volatile("s_waitcnt vmcnt(" #N ")" ::: "memory"); } while (0)
#define WAITLGKM do { asm volatile("s_waitcnt lgkmcnt(0)" ::: "memory"); } while (0)

static __device__ __forceinline__ u16 f2bf(float f) {   // native cast -> v_cvt_pk_bf16_f32 (RNE)
  union { __bf16 h; u16 u; } cv;
  cv.h = (__bf16)f;
  return cv.u;
}

static __device__ __forceinline__ void gload16(const void* g, void* l) {
  __builtin_amdgcn_global_load_lds((const __attribute__((address_space(1))) unsigned int*)g,
                                   (__attribute__((address_space(3))) unsigned int*)l,
                                   16, 0, 0);
}

// ---------------- init: zero cursor, identity/pad slot map ----------------
__global__ void init_kernel(int* order, int* tile_expert, int* cursor) {
  int i = blockIdx.x * 256 + threadIdx.x;      // grid 56*256 = 14336
  if (i < SLOTS) order[i] = (i < NTOK) ? i : -1;
  if (i < NTILES) tile_expert[i] = (i < 16) ? 8 : -1;   // tiles 0..15 = shared expert
  if (i < NEXP) cursor[i] = 0;
}

// ---------------- router + X->bf16 fused: 1 wave/token, NO global atomics ----------------
__global__ __launch_bounds__(256) void router_kernel(
    const float* __restrict__ X, const float* __restrict__ rw,
    u16* __restrict__ Xb,
    float* __restrict__ w01, int* __restrict__ e01,
    float* __restrict__ pP, int* __restrict__ pC) {
  __shared__ float wP[4][8];
  __shared__ int wE[4][2];
  const int tid = threadIdx.x;
  const int w = tid >> 6, l = tid & 63;
  const int wid = blockIdx.x * 4 + w;   // token
  const float* x = X + (size_t)wid * CDIM;
  u16* xbrow = Xb + (size_t)wid * CDIM;
  float s[8] = {0.f,0.f,0.f,0.f,0.f,0.f,0.f,0.f};
#pragma unroll 4
  for (int i = 0; i < 16; ++i) {
    int c = i * 64 + l;
    float xv = x[c];
    xbrow[c] = f2bf(xv);                // fused bf16 conversion
    const float4* rp = (const float4*)(rw + c * 8);
    float4 r0 = rp[0], r1 = rp[1];
    s[0] += xv * r0.x; s[1] += xv * r0.y; s[2] += xv * r0.z; s[3] += xv * r0.w;
    s[4] += xv * r1.x; s[5] += xv * r1.y; s[6] += xv * r1.z; s[7] += xv * r1.w;
  }
#pragma unroll
  for (int off = 32; off; off >>= 1)
#pragma unroll
    for (int e = 0; e < 8; ++e) s[e] += __shfl_down(s[e], off);
  if (l == 0) {
    float m = s[0];
#pragma unroll
    for (int e = 1; e < 8; ++e) m = fmaxf(m, s[e]);
    float p[8], d = 0.f;
#pragma unroll
    for (int e = 0; e < 8; ++e) { p[e] = expf(s[e] - m); d += p[e]; }
    float inv = 1.f / d;
#pragma unroll
    for (int e = 0; e < 8; ++e) p[e] *= inv;
    int e0 = 0;
#pragma unroll
    for (int e = 1; e < 8; ++e) if (p[e] > p[e0]) e0 = e;   // ties -> lowest idx (jax)
    int e1 = -1;
#pragma unroll
    for (int e = 0; e < 8; ++e) if (e != e0 && (e1 < 0 || p[e] > p[e1])) e1 = e;
    w01[wid * 2] = p[e0]; w01[wid * 2 + 1] = p[e1];
    e01[wid * 2] = e0;    e01[wid * 2 + 1] = e1;
#pragma unroll
    for (int e = 0; e < 8; ++e) wP[w][e] = p[e];
    wE[w][0] = e0; wE[w][1] = e1;
  }
  __syncthreads();
  if (tid < 8) {
    pP[blockIdx.x * 8 + tid] = wP[0][tid] + wP[1][tid] + wP[2][tid] + wP[3][tid];
    int c = 0;
#pragma unroll
    for (int v = 0; v < 4; ++v) c += (wE[v][0] == tid) + (wE[v][1] == tid);
    pC[blockIdx.x * 8 + tid] = c;
  }
}

// ---------------- setup: reduce partials, offsets (256-aligned), tile map, aux ----------------
__global__ __launch_bounds__(256) void setup_kernel(
    const float* __restrict__ pP, const int* __restrict__ pC,
    int* __restrict__ roff, int* __restrict__ tile_expert, float* __restrict__ out_aux) {
  __shared__ float sP[32][8];
  __shared__ int   sC[32][8];
  const int tid = threadIdx.x;
  const int e = tid & 7, g = tid >> 3;   // 32 groups x 8 experts
  float fs = 0.f; int cs = 0;
  for (int b = g; b < RBLK; b += 32) { fs += pP[b * 8 + e]; cs += pC[b * 8 + e]; }
  sP[g][e] = fs; sC[g][e] = cs;
  __syncthreads();
  if (tid == 0) {
    float P[8]; int C[8];
    for (int e2 = 0; e2 < 8; ++e2) {
      float f2 = 0.f; int c2 = 0;
      for (int g2 = 0; g2 < 32; ++g2) { f2 += sP[g2][e2]; c2 += sC[g2][e2]; }
      P[e2] = f2; C[e2] = c2;
    }
    int off = NTOK;
    float a = 0.f;
    for (int e2 = 0; e2 < NEXP; ++e2) {
      roff[e2] = off;
      int nt = (C[e2] + 255) >> 8;
      int t0 = off >> 8;
      for (int i = 0; i < nt; ++i) tile_expert[t0 + i] = e2;
      off += nt << 8;
      a += (C[e2] * (1.f / NTOK)) * (P[e2] * (1.f / NTOK));
    }
    out_aux[0] = (float)NEXP * a;
  }
}

// ---------------- scatter: token -> slots, block-aggregated cursor ----------------
__global__ __launch_bounds__(256) void scatter_kernel(
    const int* __restrict__ e01, const int* __restrict__ roff,
    int* __restrict__ cursor, int* __restrict__ order, int* __restrict__ slot_of) {
  __shared__ int cnt_l[8];
  __shared__ int base_l[8];
  const int tid = threadIdx.x;
  const int t = blockIdx.x * 256 + tid;   // grid 16 blocks
  if (tid < 8) cnt_l[tid] = 0;
  __syncthreads();
  int e0 = e01[t * 2], e1 = e01[t * 2 + 1];
  int p0 = atomicAdd(&cnt_l[e0], 1);      // LDS atomics
  int p1 = atomicAdd(&cnt_l[e1], 1);
  __syncthreads();
  if (tid < 8) base_l[tid] = atomicAdd(&cursor[tid], cnt_l[tid]);  // 8 global atomics/block
  __syncthreads();
  int s0 = roff[e0] + base_l[e0] + p0;
  int s1 = roff[e1] + base_l[e1] + p1;
  order[s0] = t; order[s1] = t;
  slot_of[t * 2] = s0; slot_of[t * 2 + 1] = s1;
}

// LDS layout: per 256x32 operand sub-image, 16 chunks of 1KB; chunk g =
// rows 16g..16g+15, slot l = (row 16g+(l&15), k (l>>4)*8..+7). All LDS ops
// wave-uniform-base + disjoint 16B slots -> zero bank conflicts (R3-R17).
// Both GEMMs: BK=64 super-tiles (two sub-images), A 3x32KB gload16 dist-2,
// B 2x32KB reg-staged (bq0/bq1), tail WAITVM(4), one barrier per super-tile.

// ---------------- GEMM1: hidden = relu(A @ W1 + b1), W1 fp32 [C][H], out bf16 ----------------
__global__ __launch_bounds__(512, 2) void gemm_h_kernel(
    const u16* __restrict__ Xb, const float* __restrict__ W1, const float* __restrict__ RW1,
    const float* __restrict__ sh_b1, const float* __restrict__ rt_b1,
    const int* __restrict__ tile_expert, const int* __restrict__ order,
    u16* __restrict__ Hu) {
  // bijective XCD swizzle, TILE-FAST decode: nwg = 896 = 8 XCD x 112;
  // consecutive wg -> consecutive tiles at same nidx (B-panel L2 reuse).
  const int orig = blockIdx.y * 16 + blockIdx.x;
  const int wg = (orig & 7) * 112 + (orig >> 3);
  const int tile = wg % 56, nidx = wg / 56;
  int e = tile_expert[tile];
  if (e < 0) return;
  const float* Bw = (e == 8) ? W1 : RW1 + (size_t)e * CDIM * HDIM;   // [C][H] fp32
  const float* bias = (e == 8) ? sh_b1 : rt_b1 + e * HDIM;

  __shared__ u16 LDS[81920];   // 160KB: A 3x16384 + B 2x16384; epilogue [128][264]
  u16* As = LDS;
  u16* Bs = LDS + 49152;

  const int tid = threadIdx.x;
  const int l = tid & 63, w = tid >> 6;     // 8 waves
  const int wm = w >> 2, wn = w & 3;        // 2M x 4N (wave tile 128x64)
  const int fr = l & 15, fq = l >> 4;
  const int m0 = tile * 256, n0 = nidx * 256;

  int tok0 = order[m0 + 32 * w + fr];      if (tok0 < 0) tok0 = 0;
  int tok1 = order[m0 + 32 * w + 16 + fr]; if (tok1 < 0) tok1 = 0;
  const u16* aSrc0 = Xb + (size_t)tok0 * CDIM + fq * 8;
  const u16* aSrc1 = Xb + (size_t)tok1 * CDIM + fq * 8;
  auto STAGE_A = [&](int bi, int kofs) {   // super-tile: two 32-k sub-images
    u16* base = As + bi * 16384;
    gload16(aSrc0 + kofs,      base + (2 * w + 0) * 512);
    gload16(aSrc1 + kofs,      base + (2 * w + 1) * 512);
    gload16(aSrc0 + kofs + 32, base + 8192 + (2 * w + 0) * 512);
    gload16(aSrc1 + kofs + 32, base + 8192 + (2 * w + 1) * 512);
  };

  // B: fp32 [CDIM][HDIM]; lane covers n = n0+32w+(l&31), k base (l>>5)*16
  const float* bSrc = Bw + (size_t)((l >> 5) * 16) * HDIM + (n0 + 32 * w + (l & 31));
  float bq0[16], bq1[16];
  auto LOAD_B = [&](int T) {
    const float* s0 = bSrc + (size_t)T * 64 * HDIM;
    const float* s1 = s0 + (size_t)32 * HDIM;
#pragma unroll
    for (int j = 0; j < 16; ++j) bq0[j] = s0[(size_t)j * HDIM];
#pragma unroll
    for (int j = 0; j < 16; ++j) bq1[j] = s1[(size_t)j * HDIM];
  };
  u16* bBase = Bs + (2 * w + ((l & 31) >> 4)) * 512 + (l & 15) * 8 + (l >> 5) * 256;
  auto WRITE_B = [&](int bi) {
    u16x8 v0, v1, v2, v3;
#pragma unroll
    for (int j = 0; j < 8; ++j) {
      v0[j] = f2bf(bq0[j]); v1[j] = f2bf(bq0[8 + j]);
      v2[j] = f2bf(bq1[j]); v3[j] = f2bf(bq1[8 + j]);
    }
    *(u16x8*)(bBase + bi * 16384) = v0;
    *(u16x8*)(bBase + bi * 16384 + 128) = v1;
    *(u16x8*)(bBase + bi * 16384 + 8192) = v2;
    *(u16x8*)(bBase + bi * 16384 + 8192 + 128) = v3;
  };

  float bvf[4];
#pragma unroll
  for (int j = 0; j < 4; ++j) bvf[j] = bias[n0 + wn * 64 + j * 16 + fr];

  f32x4 acc[8][4] = {};
  const int NT = CDIM / 64;   // 16 super-tiles
  STAGE_A(0, 0); STAGE_A(1, 64);
  LOAD_B(0);
  WAITVM(0);
  WRITE_B(0);
  LOAD_B(1);
  WAITLGKM;
  __builtin_amdgcn_s_barrier();
  __builtin_amdgcn_sched_barrier(0);

#pragma unroll 1
  for (int t = 0; t < NT; ++t) {
    if (t + 2 < NT) STAGE_A((t + 2) % 3, (t + 2) * 64);
    const u16* ab = As + (t % 3) * 16384 + l * 8;
    const u16* bb = Bs + (t & 1) * 16384 + l * 8;
    // ---- sub-image 0 (k 0..31) ----
    {
      bf16x8 av[4], bv[4], aw[4];
#pragma unroll
      for (int j = 0; j < 4; ++j) bv[j] = *(const bf16x8*)&bb[(wn * 4 + j) * 512];
#pragma unroll
      for (int i = 0; i < 4; ++i) av[i] = *(const bf16x8*)&ab[(wm * 8 + i) * 512];
#pragma unroll
      for (int i = 0; i < 4; ++i) aw[i] = *(const bf16x8*)&ab[(wm * 8 + 4 + i) * 512];
      __builtin_amdgcn_s_setprio(1);
#pragma unroll
      for (int i = 0; i < 4; ++i)
#pragma unroll
        for (int j = 0; j < 4; ++j)
          acc[i][j] = __builtin_amdgcn_mfma_f32_16x16x32_bf16(av[i], bv[j], acc[i][j], 0, 0, 0);
#pragma unroll
      for (int i = 0; i < 4; ++i)
#pragma unroll
        for (int j = 0; j < 4; ++j)
          acc[4 + i][j] = __builtin_amdgcn_mfma_f32_16x16x32_bf16(aw[i], bv[j], acc[4 + i][j], 0, 0, 0);
      __builtin_amdgcn_s_setprio(0);
    }
    // ---- sub-image 1 (k 32..63) ----
    {
      const u16* ab1 = ab + 8192;
      const u16* bb1 = bb + 8192;
      bf16x8 av[4], bv[4], aw[4];
#pragma unroll
      for (int j = 0; j < 4; ++j) bv[j] = *(const bf16x8*)&bb1[(wn * 4 + j) * 512];
#pragma unroll
      for (int i = 0; i < 4; ++i) av[i] = *(const bf16x8*)&ab1[(wm * 8 + i) * 512];
#pragma unroll
      for (int i = 0; i < 4; ++i) aw[i] = *(const bf16x8*)&ab1[(wm * 8 + 4 + i) * 512];
      __builtin_amdgcn_s_setprio(1);
#pragma unroll
      for (int i = 0; i < 4; ++i)
#pragma unroll
        for (int j = 0; j < 4; ++j)
          acc[i][j] = __builtin_amdgcn_mfma_f32_16x16x32_bf16(av[i], bv[j], acc[i][j], 0, 0, 0);
#pragma unroll
      for (int i = 0; i < 4; ++i)
#pragma unroll
        for (int j = 0; j < 4; ++j)
          acc[4 + i][j] = __builtin_amdgcn_mfma_f32_16x16x32_bf16(aw[i], bv[j], acc[4 + i][j], 0, 0, 0);
      __builtin_amdgcn_s_setprio(0);
    }
    if (t + 1 < NT) {
      if (t + 2 < NT) { WAITVM(4); } else { WAITVM(0); }   // drain B(t+1); A(t+2) stays
      WRITE_B((t + 1) & 1);
      if (t + 2 < NT) LOAD_B(t + 2);
      WAITLGKM;
      __builtin_amdgcn_s_barrier();
      __builtin_amdgcn_sched_barrier(0);
    }
  }

  // ---- epilogue: bias+relu+bf16, LDS-coalesced stores (two 128-row halves) ----
  for (int half = 0; half < 2; ++half) {
    __syncthreads();
    if (wm == half) {
#pragma unroll
      for (int i = 0; i < 8; ++i)
#pragma unroll
        for (int j = 0; j < 4; ++j) {
          const int col = wn * 64 + j * 16 + fr;
#pragma unroll
          for (int r = 0; r < 4; ++r) {
            float v = fmaxf(acc[i][j][r] + bvf[j], 0.0f);
            LDS[(i * 16 + fq * 4 + r) * 264 + col] = f2bf(v);
          }
        }
    }
    __syncthreads();
#pragma unroll
    for (int ps = 0; ps < 8; ++ps) {
      int idx = ps * 512 + tid, row = idx >> 5, c = idx & 31;
      u16x8 vv = *(const u16x8*)&LDS[row * 264 + c * 8];
      *(u16x8*)&Hu[(size_t)(m0 + half * 128 + row) * HDIM + n0 + c * 8] = vv;
    }
  }
}

// ---------------- GEMM2: Yu = Hu @ W2 + b2, W2 fp32 [H][C], fp32 out ----------------
// 256x256 tile, BK=64 super-tiles, 160KB LDS (R17: ~905 TF).
__global__ __launch_bounds__(512, 2) void gemm_o_kernel(
    const u16* __restrict__ Hu, const float* __restrict__ W2, const float* __restrict__ RW2,
    const float* __restrict__ sh_b2, const float* __restrict__ rt_b2,
    const int* __restrict__ tile_expert,
    float* __restrict__ Yu) {
  // bijective XCD swizzle: nwg = 4*56 = 224, q = 28
  const int orig = blockIdx.y * 4 + blockIdx.x;
  const int wg = (orig & 7) * 28 + (orig >> 3);
  const int tile = wg >> 2, nidx = wg & 3;
  int e = tile_expert[tile];
  if (e < 0) return;
  const float* Bw = (e == 8) ? W2 : RW2 + (size_t)e * HDIM * CDIM;   // [H][C] fp32
  const float* bias = (e == 8) ? sh_b2 : rt_b2 + e * CDIM;

  __shared__ u16 LDS2[81920];  // 160KB: A 3x16384 u16 + B 2x16384 u16
  u16* As = LDS2;
  u16* Bs = LDS2 + 49152;

  const int tid = threadIdx.x;
  const int l = tid & 63, w = tid >> 6;
  const int wm = w >> 2, wn = w & 3;        // 2M x 4N (wave tile 128x64)
  const int fr = l & 15, fq = l >> 4;
  const int m0 = tile * 256, n0 = nidx * 256;

  const u16* aSrc0 = Hu + (size_t)(m0 + 32 * w + fr) * HDIM + fq * 8;
  const u16* aSrc1 = Hu + (size_t)(m0 + 32 * w + 16 + fr) * HDIM + fq * 8;
  auto STAGE_A = [&](int bi, int kofs) {   // super-tile: two 32-k sub-images
    u16* base = As + bi * 16384;
    gload16(aSrc0 + kofs,      base + (2 * w + 0) * 512);
    gload16(aSrc1 + kofs,      base + (2 * w + 1) * 512);
    gload16(aSrc0 + kofs + 32, base + 8192 + (2 * w + 0) * 512);
    gload16(aSrc1 + kofs + 32, base + 8192 + (2 * w + 1) * 512);
  };

  const float* bSrc = Bw + (size_t)((l >> 5) * 16) * CDIM + (n0 + 32 * w + (l & 31));
  float bq0[16], bq1[16];   // named (static) reg buffers for the two k-halves
  auto LOAD_B = [&](int T) {   // 32 loads: k = T*64 + {0,32} + (l>>5)*16 + j
    const float* s0 = bSrc + (size_t)T * 64 * CDIM;
    const float* s1 = s0 + (size_t)32 * CDIM;
#pragma unroll
    for (int j = 0; j < 16; ++j) bq0[j] = s0[(size_t)j * CDIM];
#pragma unroll
    for (int j = 0; j < 16; ++j) bq1[j] = s1[(size_t)j * CDIM];
  };
  u16* bBase = Bs + (2 * w + ((l & 31) >> 4)) * 512 + (l & 15) * 8 + (l >> 5) * 256;
  auto WRITE_B = [&](int bi) {
    u16x8 v0, v1, v2, v3;
#pragma unroll
    for (int j = 0; j < 8; ++j) {
      v0[j] = f2bf(bq0[j]); v1[j] = f2bf(bq0[8 + j]);
      v2[j] = f2bf(bq1[j]); v3[j] = f2bf(bq1[8 + j]);
    }
    *(u16x8*)(bBase + bi * 16384) = v0;
    *(u16x8*)(bBase + bi * 16384 + 128) = v1;
    *(u16x8*)(bBase + bi * 16384 + 8192) = v2;
    *(u16x8*)(bBase + bi * 16384 + 8192 + 128) = v3;
  };

  float bvf[4];
#pragma unroll
  for (int j = 0; j < 4; ++j) bvf[j] = bias[n0 + wn * 64 + j * 16 + fr];

  f32x4 acc[8][4] = {};
  const int NT = HDIM / 64;   // 64 super-tiles
  STAGE_A(0, 0); STAGE_A(1, 64);
  LOAD_B(0);
  WAITVM(0);
  WRITE_B(0);
  LOAD_B(1);
  WAITLGKM;
  __builtin_amdgcn_s_barrier();
  __builtin_amdgcn_sched_barrier(0);

#pragma unroll 1
  for (int t = 0; t < NT; ++t) {
    if (t + 2 < NT) STAGE_A((t + 2) % 3, (t + 2) * 64);
    const u16* ab = As + (t % 3) * 16384 + l * 8;
    const u16* bb = Bs + (t & 1) * 16384 + l * 8;
    // ---- sub-image 0 (k 0..31) ----
    {
      bf16x8 av[4], bv[4], aw[4];
#pragma unroll
      for (int j = 0; j < 4; ++j) bv[j] = *(const bf16x8*)&bb[(wn * 4 + j) * 512];
#pragma unroll
      for (int i = 0; i < 4; ++i) av[i] = *(const bf16x8*)&ab[(wm * 8 + i) * 512];
#pragma unroll
      for (int i = 0; i < 4; ++i) aw[i] = *(const bf16x8*)&ab[(wm * 8 + 4 + i) * 512];
      __builtin_amdgcn_s_setprio(1);
#pragma unroll
      for (int i = 0; i < 4; ++i)
#pragma unroll
        for (int j = 0; j < 4; ++j)
          acc[i][j] = __builtin_amdgcn_mfma_f32_16x16x32_bf16(av[i], bv[j], acc[i][j], 0, 0, 0);
#pragma unroll
      for (int i = 0; i < 4; ++i)
#pragma unroll
        for (int j = 0; j < 4; ++j)
          acc[4 + i][j] = __builtin_amdgcn_mfma_f32_16x16x32_bf16(aw[i], bv[j], acc[4 + i][j], 0, 0, 0);
      __builtin_amdgcn_s_setprio(0);
    }
    // ---- sub-image 1 (k 32..63) ----
    {
      const u16* ab1 = ab + 8192;
      const u16* bb1 = bb + 8192;
      bf16x8 av[4], bv[4], aw[4];
#pragma unroll
      for (int j = 0; j < 4; ++j) bv[j] = *(const bf16x8*)&bb1[(wn * 4 + j) * 512];
#pragma unroll
      for (int i = 0; i < 4; ++i) av[i] = *(const bf16x8*)&ab1[(wm * 8 + i) * 512];
#pragma unroll
      for (int i = 0; i < 4; ++i) aw[i] = *(const bf16x8*)&ab1[(wm * 8 + 4 + i) * 512];
      __builtin_amdgcn_s_setprio(1);
#pragma unroll
      for (int i = 0; i < 4; ++i)
#pragma unroll
        for (int j = 0; j < 4; ++j)
          acc[i][j] = __builtin_amdgcn_mfma_f32_16x16x32_bf16(av[i], bv[j], acc[i][j], 0, 0, 0);
#pragma unroll
      for (int i = 0; i < 4; ++i)
#pragma unroll
        for (int j = 0; j < 4; ++j)
          acc[4 + i][j] = __builtin_amdgcn_mfma_f32_16x16x32_bf16(aw[i], bv[j], acc[4 + i][j], 0, 0, 0);
      __builtin_amdgcn_s_setprio(0);
    }
    if (t + 1 < NT) {
      if (t + 2 < NT) { WAITVM(4); } else { WAITVM(0); }   // drain B(t+1) 32; A(t+2) 4 stay
      WRITE_B((t + 1) & 1);
      if (t + 2 < NT) LOAD_B(t + 2);
      WAITLGKM;
      __builtin_amdgcn_s_barrier();
      __builtin_amdgcn_sched_barrier(0);
    }
  }

  const size_t mb = m0 + wm * 128;
#pragma unroll
  for (int j = 0; j < 4; ++j) {
    const int n_g = n0 + wn * 64 + j * 16 + fr;
#pragma unroll
    for (int i = 0; i < 8; ++i)
#pragma unroll
      for (int r = 0; r < 4; ++r)
        Yu[(mb + i * 16 + fq * 4 + r) * (size_t)CDIM + n_g] = acc[i][j][r] + bvf[j];
  }
}

// ---------------- combine: out = shared + w0*expert0 + w1*expert1 ----------------
__global__ void combine_kernel(const float* __restrict__ Yu, const float* __restrict__ w01,
                               const int* __restrict__ slot_of, float* __restrict__ out) {
  int gid = blockIdx.x * 256 + threadIdx.x;   // 4096 blocks; 256 float4 per token row
  int t = gid >> 8;
  int c4 = gid & 255;
  int s0 = slot_of[t * 2], s1 = slot_of[t * 2 + 1];
  float wq0 = w01[t * 2], wq1 = w01[t * 2 + 1];
  float4 a  = ((const float4*)(Yu + (size_t)t  * CDIM))[c4];
  float4 b0 = ((const float4*)(Yu + (size_t)s0 * CDIM))[c4];
  float4 b1 = ((const float4*)(Yu + (size_t)s1 * CDIM))[c4];
  float4 rv;
  rv.x = a.x + wq0 * b0.x + wq1 * b1.x;
  rv.y = a.y + wq0 * b0.y + wq1 * b1.y;
  rv.z = a.z + wq0 * b0.z + wq1 * b1.z;
  rv.w = a.w + wq0 * b0.w + wq1 * b1.w;
  ((float4*)out)[gid] = rv;
}

extern "C" void kernel_launch(void* const* d_in, const int* in_sizes, int n_in,
                              void* d_out, int out_size, void* d_ws, size_t ws_size,
                              hipStream_t stream) {
  const float* X        = (const float*)d_in[0];   // [4096,1024]
  const float* router_w = (const float*)d_in[1];   // [1024,8]
  const float* sh_w1    = (const float*)d_in[2];   // [1024,4096]  [C][H]
  const float* sh_b1    = (const float*)d_in[3];   // [4096]
  const float* sh_w2    = (const float*)d_in[4];   // [4096,1024]  [H][C]
  const float* sh_b2    = (const float*)d_in[5];   // [1024]
  const float* rt_w1    = (const float*)d_in[6];   // [8,1024,4096]
  const float* rt_b1    = (const float*)d_in[7];   // [8,4096]
  const float* rt_w2    = (const float*)d_in[8];   // [8,4096,1024]
  const float* rt_b2    = (const float*)d_in[9];   // [8,1024]
  float* out = (float*)d_out;

  // ---- workspace layout ----
  char* p = (char*)d_ws;
  auto take = [&](size_t bytes) { char* q = p; p += (bytes + 255) & ~(size_t)255; return q; };
  u16*  Xb   = (u16*)take((size_t)NTOK * CDIM * 2);        //   8 MB
  u16*  Hu   = (u16*)take((size_t)SLOTS * HDIM * 2);       // 112 MB
  float* Yu  = (float*)take((size_t)SLOTS * CDIM * 4);     //  56 MB
  float* w01 = (float*)take((size_t)NTOK * 2 * 4);
  int*  e01  = (int*)take((size_t)NTOK * 2 * 4);
  int*  slot_of = (int*)take((size_t)NTOK * 2 * 4);
  int*  order   = (int*)take((size_t)SLOTS * 4);
  int*  tile_expert = (int*)take((size_t)NTILES * 4);
  float* pP  = (float*)take((size_t)RBLK * 8 * 4);         //  32 KB router prob partials
  int*  pC   = (int*)take((size_t)RBLK * 8 * 4);           //  32 KB router count partials
  int*  cursor = (int*)take(256);
  int*  roff   = (int*)take(256);
  size_t need = (size_t)(p - (char*)d_ws);
  if (ws_size < need) return;  // insufficient scratch -> fail visibly (poisoned out)

  // ---- pipeline ----
  init_kernel<<<NTILES, 256, 0, stream>>>(order, tile_expert, cursor);
  router_kernel<<<RBLK, 256, 0, stream>>>(X, router_w, Xb, w01, e01, pP, pC);
  setup_kernel<<<1, 256, 0, stream>>>(pP, pC, roff, tile_expert, out + (size_t)NTOK * CDIM);
  scatter_kernel<<<NTOK / 256, 256, 0, stream>>>(e01, roff, cursor, order, slot_of);
  gemm_h_kernel<<<dim3(16, NTILES), 512, 0, stream>>>(
      Xb, sh_w1, rt_w1, sh_b1, rt_b1, tile_expert, order, Hu);
  gemm_o_kernel<<<dim3(4, NTILES), 512, 0, stream>>>(
      Hu, sh_w2, rt_w2, sh_b2, rt_b2, tile_expert, Yu);
  combine_kernel<<<(NTOK * CDIM / 4) / 256, 256, 0, stream>>>(Yu, w01, slot_of, out);
}